// Round 12
// baseline (348.073 us; speedup 1.0000x reference)
//
#include <hip/hip_runtime.h>
#include <hip/hip_bf16.h>
#include <math.h>

static constexpr float NEG_SLOPE = 0.2f;
static constexpr float NEG_BIG = -3.0e38f;  // finite sentinel: avoids (-inf)-(-inf)=NaN

typedef __attribute__((ext_vector_type(8))) short short8;  // 8 bf16 (4 VGPRs)
typedef __attribute__((ext_vector_type(4))) float f32x4;

__device__ __forceinline__ float blo(unsigned u) { return __uint_as_float(u << 16); }
__device__ __forceinline__ float bhi(unsigned u) { return __uint_as_float(u & 0xffff0000u); }
// hi bf16 read WITHOUT masking: low 16 bits are <=2^-8 relative mantissa noise.
__device__ __forceinline__ float bhiraw(unsigned u) { return __uint_as_float(u); }
__device__ __forceinline__ unsigned pack2(float a, float b) {
  __hip_bfloat162 t = __float22bfloat162_rn(make_float2(a, b));
  union { __hip_bfloat162 b; unsigned u; } v;
  v.b = t;
  return v.u;
}

#define FMA8(V, A)                         \
  acc[0] = fmaf(blo((V).x), (A), acc[0]);  \
  acc[1] = fmaf(bhi((V).x), (A), acc[1]);  \
  acc[2] = fmaf(blo((V).y), (A), acc[2]);  \
  acc[3] = fmaf(bhi((V).y), (A), acc[3]);  \
  acc[4] = fmaf(blo((V).z), (A), acc[4]);  \
  acc[5] = fmaf(bhi((V).z), (A), acc[5]);  \
  acc[6] = fmaf(blo((V).w), (A), acc[6]);  \
  acc[7] = fmaf(bhi((V).w), (A), acc[7])

#define FMA8R(V, A)                           \
  acc[0] = fmaf(blo((V).x), (A), acc[0]);     \
  acc[1] = fmaf(bhiraw((V).x), (A), acc[1]);  \
  acc[2] = fmaf(blo((V).y), (A), acc[2]);     \
  acc[3] = fmaf(bhiraw((V).y), (A), acc[3]);  \
  acc[4] = fmaf(blo((V).z), (A), acc[4]);     \
  acc[5] = fmaf(bhiraw((V).z), (A), acc[5]);  \
  acc[6] = fmaf(blo((V).w), (A), acc[6]);     \
  acc[7] = fmaf(bhiraw((V).w), (A), acc[7])

// ---- W prep (device fn): fp32 [k][col] -> bf16 swizzled [col][k] image + 16
// extra cols of WA = W@A so the GEMM emits logits as a free tile.
template <int BN, int HEADS>
__device__ void prep_w(const float* __restrict__ W, const float* __restrict__ as_,
                       const float* __restrict__ ad_, uint4* __restrict__ out, int i) {
  constexpr int XC = BN + 16;
  constexpr int C = BN / HEADS;
  if (i >= XC * 16) return;
  const int col = i >> 4;
  const int chunk = (i & 15) ^ (col & 7);
  float v[8];
  if (col < BN) {
#pragma unroll
    for (int t = 0; t < 8; ++t) v[t] = W[(size_t)(chunk * 8 + t) * BN + col];
  } else {
    const int j = col - BN;
#pragma unroll
    for (int t = 0; t < 8; ++t) v[t] = 0.f;
    if (j < 2 * HEADS) {
      const int hh = (HEADS == 4) ? (j & 3) : 0;
      const bool is_src = (HEADS == 4) ? (j < 4) : (j == 0);
      const float* av = (is_src ? as_ : ad_) + hh * C;
      const float* wb = W + hh * C;
#pragma unroll
      for (int t = 0; t < 8; ++t) {
        float s = 0.f;
        for (int c = 0; c < C; ++c) s = fmaf(wb[(size_t)(chunk * 8 + t) * BN + c], av[c], s);
        v[t] = s;
      }
    }
  }
  uint4 u;
  u.x = pack2(v[0], v[1]);
  u.y = pack2(v[2], v[3]);
  u.z = pack2(v[4], v[5]);
  u.w = pack2(v[6], v[7]);
  out[i] = u;
}

// Fused setup: blocks [0,9) prep W1; [9,14) prep W2; rest zero cnt.
__global__ void k_setup(const float* __restrict__ W1, const float* __restrict__ a1s,
                        const float* __restrict__ a1d, uint4* __restrict__ wsw1,
                        const float* __restrict__ W2, const float* __restrict__ a2s,
                        const float* __restrict__ a2d, uint4* __restrict__ wsw2,
                        int* __restrict__ cnt, int N) {
  const int b = blockIdx.x;
  const int tid = threadIdx.x;
  if (b < 9) {
    prep_w<128, 4>(W1, a1s, a1d, wsw1, b * 256 + tid);
  } else if (b < 14) {
    prep_w<64, 1>(W2, a2s, a2d, wsw2, (b - 9) * 256 + tid);
  } else {
    const int i = (b - 14) * 256 + tid;
    if (i < (N >> 2)) ((int4*)cnt)[i] = make_int4(0, 0, 0, 0);
    const int r = (N & ~3) + i;  // tail (N%4 elems)
    if (i < 4 && r < N) cnt[r] = 0;
  }
}

// ---- MFMA GEMM: h = x@W (bf16), logits from extra tile. Single reused LDS buf.
template <int BN, int HEADS>
__global__ __launch_bounds__(256) void k_mfma_gemm(
    const float* __restrict__ x, const uint4* __restrict__ wsw,
    __hip_bfloat16* __restrict__ h_out, float* __restrict__ als,
    float* __restrict__ ald, int N) {
  constexpr int XC = BN + 16;
  constexpr int NTILES = BN / 16;
  constexpr int BUFSZ = (XC * 256 > 128 * 256) ? XC * 256 : 128 * 256;
  __shared__ unsigned char buf[BUFSZ];
  const int tid = threadIdx.x;
  const int lane = tid & 63;
  const int wid = tid >> 6;
  const int base = blockIdx.x * 128;

  for (int it = 0; it < 8; ++it) {
    const int i = it * 256 + tid;
    const int r = i >> 4, c = i & 15;
    const int g = base + r;
    float4 f0 = make_float4(0.f, 0.f, 0.f, 0.f), f1 = f0;
    if (g < N) {
      const float* xp = x + (size_t)g * 128 + c * 8;
      f0 = *(const float4*)xp;
      f1 = *(const float4*)(xp + 4);
    }
    uint4 u;
    u.x = pack2(f0.x, f0.y);
    u.y = pack2(f0.z, f0.w);
    u.z = pack2(f1.x, f1.y);
    u.w = pack2(f1.z, f1.w);
    *(uint4*)(buf + r * 256 + ((c * 16) ^ ((r & 7) << 4))) = u;
  }
  __syncthreads();

  const int lg = lane >> 4;
  const int ll = lane & 15;
  union U { uint4 u; short8 s; };
  short8 afr[2][4];
#pragma unroll
  for (int rt = 0; rt < 2; ++rt) {
    const int row = wid * 32 + rt * 16 + ll;
    const unsigned char* rp = buf + row * 256;
    const int swz = (row & 7) << 4;
#pragma unroll
    for (int ks = 0; ks < 4; ++ks) {
      U t;
      t.u = *(const uint4*)(rp + ((ks * 64 + lg * 16) ^ swz));
      afr[rt][ks] = t.s;
    }
  }
  __syncthreads();  // done with X region; reuse buf for W

  {
    uint4* dst = (uint4*)buf;
    for (int i = tid; i < XC * 16; i += 256) dst[i] = wsw[i];
  }
  __syncthreads();

  f32x4 acc[2][NTILES + 1];
#pragma unroll
  for (int rt = 0; rt < 2; ++rt)
#pragma unroll
    for (int t = 0; t <= NTILES; ++t) acc[rt][t] = (f32x4){0.f, 0.f, 0.f, 0.f};

#pragma unroll
  for (int t = 0; t <= NTILES; ++t) {
    const int col = t * 16 + ll;
    const unsigned char* cp = buf + col * 256;
    const int swz = (col & 7) << 4;
#pragma unroll
    for (int ks = 0; ks < 4; ++ks) {
      U b;
      b.u = *(const uint4*)(cp + ((ks * 64 + lg * 16) ^ swz));
      acc[0][t] = __builtin_amdgcn_mfma_f32_16x16x32_bf16(afr[0][ks], b.s, acc[0][t], 0, 0, 0);
      acc[1][t] = __builtin_amdgcn_mfma_f32_16x16x32_bf16(afr[1][ks], b.s, acc[1][t], 0, 0, 0);
    }
  }

#pragma unroll
  for (int rt = 0; rt < 2; ++rt) {
#pragma unroll
    for (int r = 0; r < 4; ++r) {
      const int row = base + wid * 32 + rt * 16 + lg * 4 + r;
      if (row < N) {
        const float v = acc[rt][NTILES][r];
        if (HEADS == 4) {
          if (ll < 4) als[(size_t)row * 4 + ll] = v;
          else if (ll < 8) ald[(size_t)row * 4 + (ll - 4)] = v;
        } else {
          if (ll == 0) als[row] = v;
          else if (ll == 1) ald[row] = v;
        }
      }
    }
  }

  __syncthreads();
#pragma unroll
  for (int rt = 0; rt < 2; ++rt) {
#pragma unroll
    for (int t = 0; t < NTILES; ++t) {
#pragma unroll
      for (int r = 0; r < 4; ++r) {
        const float v = acc[rt][t][r];
        const float vn = __shfl_xor(v, 1, 64);
        if (!(lane & 1)) {
          const int row = wid * 32 + rt * 16 + lg * 4 + r;
          *(unsigned*)(buf + row * (BN * 2) + (t * 16 + ll) * 2) = pack2(v, vn);
        }
      }
    }
  }
  __syncthreads();
  {
    constexpr int U4 = 128 * BN / 8;
    constexpr int U4R = BN / 8;
    for (int i = tid; i < U4; i += 256) {
      const int row = i / U4R;
      const int g = base + row;
      if (g < N)
        *(uint4*)((unsigned short*)h_out + (size_t)g * BN + (i % U4R) * 8) = ((uint4*)buf)[i];
    }
  }
}

// ---------------- CSR build (counting sort by dst) ----------------
__global__ void k_count(const int* __restrict__ edst, int* __restrict__ cnt, int E) {
  int i = blockIdx.x * blockDim.x + threadIdx.x;
  if (i < E) atomicAdd(cnt + edst[i], 1);
}

// +1 folded in (self-loop); cnt zeroed in k_setup.
__global__ void k_scan_local(const int* __restrict__ cnt, int* __restrict__ rowptr,
                             int* __restrict__ bsum, int N) {
  __shared__ int lds[256];
  const int tid = threadIdx.x;
  const int base = blockIdx.x * 1024;
  int vals[4], tsum = 0;
#pragma unroll
  for (int q = 0; q < 4; ++q) {
    int i = base + tid * 4 + q;
    vals[q] = (i < N) ? cnt[i] + 1 : 0;
    tsum += vals[q];
  }
  lds[tid] = tsum;
  __syncthreads();
  for (int off = 1; off < 256; off <<= 1) {
    int t = (tid >= off) ? lds[tid - off] : 0;
    __syncthreads();
    lds[tid] += t;
    __syncthreads();
  }
  int run = lds[tid] - tsum;
  if (tid == 255) bsum[blockIdx.x] = lds[255];
#pragma unroll
  for (int q = 0; q < 4; ++q) {
    int i = base + tid * 4 + q;
    if (i < N) rowptr[i] = run;
    run += vals[q];
  }
}

// Fused bsum-scan + add: every block redundantly scans bsum (<=128 entries) in
// LDS, then applies its exclusive prefix. Kills one dispatch.
__global__ void k_scan_add2(const int* __restrict__ bsum, int nb,
                            int* __restrict__ rowptr, int* __restrict__ cursor,
                            int N, int total) {
  __shared__ int pref[128];
  const int tid = threadIdx.x;
  int own = 0;
  if (tid < 128) {
    own = (tid < nb) ? bsum[tid] : 0;
    pref[tid] = own;
  }
  __syncthreads();
  for (int off = 1; off < 128; off <<= 1) {
    int t = (tid >= off && tid < 128) ? pref[tid - off] : 0;
    __syncthreads();
    if (tid < 128) pref[tid] += t;
    __syncthreads();
  }
  if (tid < 128) pref[tid] -= own;  // exclusive
  __syncthreads();
  const int i = blockIdx.x * blockDim.x + tid;
  if (i < N) {
    int r = rowptr[i] + pref[i >> 10];
    rowptr[i] = r;
    cursor[i] = r;
  } else if (i == N) {
    rowptr[N] = total;
  }
}

// Partitioned CSR fill: 2 parts -> 2 sweeps; 3.4MB write region per part
// stays L2-resident per XCD.
__global__ void k_build_part(const int* __restrict__ esrc, const int* __restrict__ edst,
                             int* __restrict__ cursor, int* __restrict__ nbr, int E, int N) {
  constexpr int NPARTS = 2;
  const int p = blockIdx.x & 1;
  const int span = (N + NPARTS - 1) / NPARTS;
  const int lo = p * span;
  const int hi = min(N, lo + span);
  const int gid = (int)(blockIdx.x >> 1) * blockDim.x + threadIdx.x;
  const int stride = (int)(gridDim.x >> 1) * blockDim.x;
  const int E4 = E >> 2;
  for (int i = gid; i < E4; i += stride) {
    const int4 d4 = ((const int4*)edst)[i];
    const int4 s4 = ((const int4*)esrc)[i];
    if (d4.x >= lo && d4.x < hi) nbr[atomicAdd(cursor + d4.x, 1)] = s4.x;
    if (d4.y >= lo && d4.y < hi) nbr[atomicAdd(cursor + d4.y, 1)] = s4.y;
    if (d4.z >= lo && d4.z < hi) nbr[atomicAdd(cursor + d4.z, 1)] = s4.z;
    if (d4.w >= lo && d4.w < hi) nbr[atomicAdd(cursor + d4.w, 1)] = s4.w;
  }
  for (int i = E4 * 4 + gid; i < E + N; i += stride) {
    const int d = i < E ? edst[i] : i - E;
    if (d >= lo && d < hi) {
      const int sn = i < E ? esrc[i] : i - E;
      nbr[atomicAdd(cursor + d, 1)] = sn;
    }
  }
}

// ---------------- Gather layer 1: H=4, C=32; two nodes/wave; 8-edge batches ----
__global__ void k_gather_l1(const int* __restrict__ rowptr, const int* __restrict__ nbr,
                            const float* __restrict__ als, const float* __restrict__ ald,
                            const __hip_bfloat16* __restrict__ hfeat,
                            const float* __restrict__ bias,
                            float* __restrict__ out, int N) {
  __shared__ float atab[4][2][4][40];    // [wave][half][head][edge]
  __shared__ unsigned otab[4][2][32];    // [wave][half][edge] byte offsets
  const int lane = threadIdx.x & 63;
  const int wid = threadIdx.x >> 6;
  const int half = lane >> 5;
  const int l32 = lane & 31;
  const int node = (int)((blockIdx.x * blockDim.x + threadIdx.x) >> 6) * 2 + half;
  const bool valid = node < N;
  int start = 0, end = 0;
  if (valid) {
    start = rowptr[node];
    end = rowptr[node + 1];
  }
  const int deg = end - start;
  const float4 aldd = valid ? ((const float4*)ald)[node] : make_float4(0.f, 0.f, 0.f, 0.f);

  float t[4];
  int myn = 0;
  {
    const int j = start + l32;
    if (j < end) {
      myn = nbr[j];
      const float4 av = ((const float4*)als)[myn];
      const float tr[4] = {av.x + aldd.x, av.y + aldd.y, av.z + aldd.z, av.w + aldd.w};
#pragma unroll
      for (int h = 0; h < 4; ++h) t[h] = tr[h] >= 0.f ? tr[h] : NEG_SLOPE * tr[h];
    } else {
#pragma unroll
      for (int h = 0; h < 4; ++h) t[h] = NEG_BIG;
    }
  }
  otab[wid][half][l32] = (unsigned)myn << 8;  // 256B rows

  float Mh[4], rden[4], myex[4];
  if (deg <= 32) {
#pragma unroll
    for (int h = 0; h < 4; ++h) {
      float M = t[h];
#pragma unroll
      for (int off = 1; off < 32; off <<= 1) M = fmaxf(M, __shfl_xor(M, off, 64));
      const float e = __expf(t[h] - M);
      float sum = e;
#pragma unroll
      for (int off = 1; off < 32; off <<= 1) sum += __shfl_xor(sum, off, 64);
      Mh[h] = M;
      rden[h] = 1.f / sum;
      myex[h] = e * rden[h];
    }
  } else {
    float m[4], s[4];
#pragma unroll
    for (int h = 0; h < 4; ++h) {
      m[h] = t[h];
      s[h] = (t[h] > NEG_BIG) ? 1.f : 0.f;
    }
    for (int b = start + 32; b < end; b += 32) {
      const int j = b + l32;
      if (j < end) {
        const int sn = nbr[j];
        const float4 av = ((const float4*)als)[sn];
        const float tr[4] = {av.x + aldd.x, av.y + aldd.y, av.z + aldd.z, av.w + aldd.w};
#pragma unroll
        for (int h = 0; h < 4; ++h) {
          const float tv = tr[h] >= 0.f ? tr[h] : NEG_SLOPE * tr[h];
          const float M = fmaxf(m[h], tv);
          s[h] = s[h] * __expf(m[h] - M) + __expf(tv - M);
          m[h] = M;
        }
      }
    }
#pragma unroll
    for (int h = 0; h < 4; ++h) {
      float M = m[h];
#pragma unroll
      for (int off = 1; off < 32; off <<= 1) M = fmaxf(M, __shfl_xor(M, off, 64));
      float e = s[h] * __expf(m[h] - M);
#pragma unroll
      for (int off = 1; off < 32; off <<= 1) e += __shfl_xor(e, off, 64);
      Mh[h] = M;
      rden[h] = 1.f / e;
      myex[h] = __expf(t[h] - M) * rden[h];
    }
  }
#pragma unroll
  for (int h = 0; h < 4; ++h) atab[wid][half][h][l32] = myex[h];

  // pass C: 8 edges per iteration (2 slots x 4 batched loads in flight)
  const int sub = l32 >> 4;
  const int q = l32 & 15;
  const int head = q >> 2;
  const char* hq = (const char*)hfeat + q * 16;
  float acc[8];
#pragma unroll
  for (int k = 0; k < 8; ++k) acc[k] = 0.f;

  const int nq = deg < 32 ? deg : 32;
  const float* ap = &atab[wid][half][head][0];
  const unsigned* op = &otab[wid][half][0];
  for (int j0 = 0; j0 < nq; j0 += 8) {
    const float a0 = ap[j0 + sub];
    const float a1 = ap[j0 + 2 + sub];
    const float a2 = ap[j0 + 4 + sub];
    const float a3 = ap[j0 + 6 + sub];
    const uint4 v0 = *(const uint4*)(hq + op[j0 + sub]);
    const uint4 v1 = *(const uint4*)(hq + op[j0 + 2 + sub]);
    const uint4 v2 = *(const uint4*)(hq + op[j0 + 4 + sub]);
    const uint4 v3 = *(const uint4*)(hq + op[j0 + 6 + sub]);
    FMA8R(v0, a0);
    FMA8R(v1, a1);
    FMA8R(v2, a2);
    FMA8R(v3, a3);
  }
  if (deg > 32) {
    const float Mm = head == 0 ? Mh[0] : head == 1 ? Mh[1] : head == 2 ? Mh[2] : Mh[3];
    const float rd = head == 0 ? rden[0] : head == 1 ? rden[1] : head == 2 ? rden[2] : rden[3];
    const float ad_ = head == 0 ? aldd.x : head == 1 ? aldd.y : head == 2 ? aldd.z : aldd.w;
    for (int j0 = 32; j0 < deg; j0 += 2) {
      const int j = j0 + sub;
      float a = 0.f;
      int sn = 0;
      if (j < deg) {
        sn = nbr[start + j];
        const float4 av = ((const float4*)als)[sn];
        const float as_ = head == 0 ? av.x : head == 1 ? av.y : head == 2 ? av.z : av.w;
        float tv = as_ + ad_;
        tv = tv >= 0.f ? tv : NEG_SLOPE * tv;
        a = __expf(tv - Mm) * rd;
      }
      const uint4 v = *(const uint4*)(hq + (size_t)sn * 256);
      FMA8R(v, a);
    }
  }

#pragma unroll
  for (int k = 0; k < 8; ++k) acc[k] += __shfl_xor(acc[k], 16, 64);
  if (valid && sub == 0) {
    const float4 b0 = ((const float4*)bias)[q * 2];
    const float4 b1 = ((const float4*)bias)[q * 2 + 1];
    float r[8] = {acc[0] + b0.x, acc[1] + b0.y, acc[2] + b0.z, acc[3] + b0.w,
                  acc[4] + b1.x, acc[5] + b1.y, acc[6] + b1.z, acc[7] + b1.w};
#pragma unroll
    for (int k = 0; k < 8; ++k) r[k] = r[k] > 0.f ? r[k] : __expf(r[k]) - 1.f;
    float4* opo = (float4*)(out + (size_t)node * 128 + q * 8);
    opo[0] = make_float4(r[0], r[1], r[2], r[3]);
    opo[1] = make_float4(r[4], r[5], r[6], r[7]);
  }
}

// ---------------- Gather layer 2: H=1, C=64; two nodes/wave; 16-edge batches ----
__global__ void k_gather_l2(const int* __restrict__ rowptr, const int* __restrict__ nbr,
                            const float* __restrict__ als, const float* __restrict__ ald,
                            const __hip_bfloat16* __restrict__ hfeat,
                            const float* __restrict__ bias,
                            float* __restrict__ out, int N) {
  __shared__ float2 atab[4][2][36];  // {alpha, off}
  const int lane = threadIdx.x & 63;
  const int wid = threadIdx.x >> 6;
  const int half = lane >> 5;
  const int l32 = lane & 31;
  const int node = (int)((blockIdx.x * blockDim.x + threadIdx.x) >> 6) * 2 + half;
  const bool valid = node < N;
  int start = 0, end = 0;
  if (valid) {
    start = rowptr[node];
    end = rowptr[node + 1];
  }
  const int deg = end - start;
  const float ald0 = valid ? ald[node] : 0.f;

  float t = NEG_BIG;
  int myn = 0;
  {
    const int j = start + l32;
    if (j < end) {
      myn = nbr[j];
      float tv = als[myn] + ald0;
      t = tv >= 0.f ? tv : NEG_SLOPE * tv;
    }
  }

  float M, rden, myal;
  if (deg <= 32) {
    M = t;
#pragma unroll
    for (int off = 1; off < 32; off <<= 1) M = fmaxf(M, __shfl_xor(M, off, 64));
    const float e = __expf(t - M);
    float sum = e;
#pragma unroll
    for (int off = 1; off < 32; off <<= 1) sum += __shfl_xor(sum, off, 64);
    rden = 1.f / sum;
    myal = e * rden;
  } else {
    float m = t, s = (t > NEG_BIG) ? 1.f : 0.f;
    for (int b = start + 32; b < end; b += 32) {
      const int j = b + l32;
      if (j < end) {
        float tv = als[nbr[j]] + ald0;
        tv = tv >= 0.f ? tv : NEG_SLOPE * tv;
        const float Mn = fmaxf(m, tv);
        s = s * __expf(m - Mn) + __expf(tv - Mn);
        m = Mn;
      }
    }
    M = m;
#pragma unroll
    for (int off = 1; off < 32; off <<= 1) M = fmaxf(M, __shfl_xor(M, off, 64));
    float e = s * __expf(m - M);
#pragma unroll
    for (int off = 1; off < 32; off <<= 1) e += __shfl_xor(e, off, 64);
    rden = 1.f / e;
    myal = __expf(t - M) * rden;
  }
  atab[wid][half][l32] = make_float2(myal, __int_as_float(myn << 7));  // 128B rows

  const int sub = l32 >> 3;  // 4 edge slots
  const int q = l32 & 7;
  const char* hq = (const char*)hfeat + q * 16;
  float acc[8];
#pragma unroll
  for (int k = 0; k < 8; ++k) acc[k] = 0.f;

  const int nq = deg < 32 ? deg : 32;
  const float2* ap = &atab[wid][half][0];
  for (int j0 = 0; j0 < nq; j0 += 16) {
    const float2 o0 = ap[j0 + sub];
    const float2 o1 = ap[j0 + 4 + sub];
    const float2 o2 = ap[j0 + 8 + sub];
    const float2 o3 = ap[j0 + 12 + sub];
    const uint4 v0 = *(const uint4*)(hq + (unsigned)__float_as_int(o0.y));
    const uint4 v1 = *(const uint4*)(hq + (unsigned)__float_as_int(o1.y));
    const uint4 v2 = *(const uint4*)(hq + (unsigned)__float_as_int(o2.y));
    const uint4 v3 = *(const uint4*)(hq + (unsigned)__float_as_int(o3.y));
    FMA8(v0, o0.x);
    FMA8(v1, o1.x);
    FMA8(v2, o2.x);
    FMA8(v3, o3.x);
  }
  if (deg > 32) {
    for (int j0 = 32; j0 < deg; j0 += 4) {
      const int j = j0 + sub;
      float a = 0.f;
      int sn = 0;
      if (j < deg) {
        sn = nbr[start + j];
        float tv = als[sn] + ald0;
        tv = tv >= 0.f ? tv : NEG_SLOPE * tv;
        a = __expf(tv - M) * rden;
      }
      const uint4 v = *(const uint4*)(hq + (size_t)sn * 128);
      FMA8(v, a);
    }
  }

#pragma unroll
  for (int k = 0; k < 8; ++k) {
    acc[k] += __shfl_xor(acc[k], 8, 64);
    acc[k] += __shfl_xor(acc[k], 16, 64);
  }
  if (valid && sub == 0) {
    const float4 b0 = ((const float4*)bias)[q * 2];
    const float4 b1 = ((const float4*)bias)[q * 2 + 1];
    float4* opo = (float4*)(out + (size_t)node * 64 + q * 8);
    opo[0] = make_float4(acc[0] + b0.x, acc[1] + b0.y, acc[2] + b0.z, acc[3] + b0.w);
    opo[1] = make_float4(acc[4] + b1.x, acc[5] + b1.y, acc[6] + b1.z, acc[7] + b1.w);
  }
}

extern "C" void kernel_launch(void* const* d_in, const int* in_sizes, int n_in,
                              void* d_out, int out_size, void* d_ws, size_t ws_size,
                              hipStream_t stream) {
  const float* x   = (const float*)d_in[0];
  const int*   ei  = (const int*)d_in[1];
  const float* W1  = (const float*)d_in[2];
  const float* a1s = (const float*)d_in[3];
  const float* a1d = (const float*)d_in[4];
  const float* b1  = (const float*)d_in[5];
  const float* W2  = (const float*)d_in[6];
  const float* a2s = (const float*)d_in[7];
  const float* a2d = (const float*)d_in[8];
  const float* b2  = (const float*)d_in[9];

  const int N = in_sizes[0] / 128;  // 100000
  const int E = in_sizes[1] / 2;    // 1600000
  const int* esrc = ei;
  const int* edst = ei + E;

  float* ws   = (float*)d_ws;
  __hip_bfloat16* h = (__hip_bfloat16*)ws;   // N*128 bf16 (slot sized N*128 f32)
  float* out1 = ws   + (size_t)N * 128;      // N*128 f32
  float* als  = out1 + (size_t)N * 128;      // N*4
  float* ald  = als  + (size_t)N * 4;        // N*4
  int* cnt    = (int*)(ald + (size_t)N * 4); // N
  int* rowptr = cnt + N;                     // N+1
  int* cursor = rowptr + N + 1;              // N
  int* bsum   = cursor + N;                  // 1024
  int* nbr    = bsum + 1024;                 // E+N
  size_t off = ((size_t)((nbr + E + N) - (int*)ws) + 3) & ~(size_t)3;
  uint4* wsw1 = (uint4*)((int*)ws + off);    // 144*16 uint4
  uint4* wsw2 = wsw1 + 144 * 16;             // 80*16 uint4

  float* outF = (float*)d_out;               // N*64

  const int total = E + N;
  const int nb = (N + 1023) / 1024;

  // ---- setup (W preps + cnt zero) + CSR build ----
  const int zb = ((N >> 2) + 255) / 256;
  k_setup<<<14 + zb, 256, 0, stream>>>(W1, a1s, a1d, wsw1, W2, a2s, a2d, wsw2, cnt, N);
  k_count<<<(E + 255) / 256, 256, 0, stream>>>(edst, cnt, E);
  k_scan_local<<<nb, 256, 0, stream>>>(cnt, rowptr, bsum, N);
  k_scan_add2<<<(N + 256) / 256, 256, 0, stream>>>(bsum, nb, rowptr, cursor, N, total);
  k_build_part<<<1280, 256, 0, stream>>>(esrc, edst, cursor, nbr, E, N);

  // ---- Layer 1: H=4, C=32, concat -> [N,128], +b1, ELU ----
  k_mfma_gemm<128, 4><<<(N + 127) / 128, 256, 0, stream>>>(x, wsw1, h, als, ald, N);
  k_gather_l1<<<(N + 7) / 8, 256, 0, stream>>>(rowptr, nbr, als, ald, h, b1, out1, N);

  // ---- Layer 2: H=1, C=64, mean(H=1) -> [N,64], +b2 ----
  k_mfma_gemm<64, 1><<<(N + 127) / 128, 256, 0, stream>>>(out1, wsw2, h, als, ald, N);
  k_gather_l2<<<(N + 7) / 8, 256, 0, stream>>>(rowptr, nbr, als, ald, h, b2, outF, N);
}

// Round 13
// 320.385 us; speedup vs baseline: 1.0864x; 1.0864x over previous
//
#include <hip/hip_runtime.h>
#include <hip/hip_bf16.h>
#include <math.h>

static constexpr float NEG_SLOPE = 0.2f;
static constexpr float NEG_BIG = -3.0e38f;  // finite sentinel: avoids (-inf)-(-inf)=NaN

typedef __attribute__((ext_vector_type(8))) short short8;  // 8 bf16 (4 VGPRs)
typedef __attribute__((ext_vector_type(4))) float f32x4;

__device__ __forceinline__ float blo(unsigned u) { return __uint_as_float(u << 16); }
__device__ __forceinline__ float bhi(unsigned u) { return __uint_as_float(u & 0xffff0000u); }
// hi bf16 read WITHOUT masking: low 16 bits are <=2^-8 relative mantissa noise.
__device__ __forceinline__ float bhiraw(unsigned u) { return __uint_as_float(u); }
__device__ __forceinline__ unsigned pack2(float a, float b) {
  __hip_bfloat162 t = __float22bfloat162_rn(make_float2(a, b));
  union { __hip_bfloat162 b; unsigned u; } v;
  v.b = t;
  return v.u;
}

#define FMA8(V, A)                         \
  acc[0] = fmaf(blo((V).x), (A), acc[0]);  \
  acc[1] = fmaf(bhi((V).x), (A), acc[1]);  \
  acc[2] = fmaf(blo((V).y), (A), acc[2]);  \
  acc[3] = fmaf(bhi((V).y), (A), acc[3]);  \
  acc[4] = fmaf(blo((V).z), (A), acc[4]);  \
  acc[5] = fmaf(bhi((V).z), (A), acc[5]);  \
  acc[6] = fmaf(blo((V).w), (A), acc[6]);  \
  acc[7] = fmaf(bhi((V).w), (A), acc[7])

#define FMA8R(V, A)                           \
  acc[0] = fmaf(blo((V).x), (A), acc[0]);     \
  acc[1] = fmaf(bhiraw((V).x), (A), acc[1]);  \
  acc[2] = fmaf(blo((V).y), (A), acc[2]);     \
  acc[3] = fmaf(bhiraw((V).y), (A), acc[3]);  \
  acc[4] = fmaf(blo((V).z), (A), acc[4]);     \
  acc[5] = fmaf(bhiraw((V).z), (A), acc[5]);  \
  acc[6] = fmaf(blo((V).w), (A), acc[6]);     \
  acc[7] = fmaf(bhiraw((V).w), (A), acc[7])

// ---- W prep (device fn): fp32 [k][col] -> bf16 swizzled [col][k] image + 16
// extra cols of WA = W@A so the GEMM emits logits as a free tile.
template <int BN, int HEADS>
__device__ void prep_w(const float* __restrict__ W, const float* __restrict__ as_,
                       const float* __restrict__ ad_, uint4* __restrict__ out, int i) {
  constexpr int XC = BN + 16;
  constexpr int C = BN / HEADS;
  if (i >= XC * 16) return;
  const int col = i >> 4;
  const int chunk = (i & 15) ^ (col & 7);
  float v[8];
  if (col < BN) {
#pragma unroll
    for (int t = 0; t < 8; ++t) v[t] = W[(size_t)(chunk * 8 + t) * BN + col];
  } else {
    const int j = col - BN;
#pragma unroll
    for (int t = 0; t < 8; ++t) v[t] = 0.f;
    if (j < 2 * HEADS) {
      const int hh = (HEADS == 4) ? (j & 3) : 0;
      const bool is_src = (HEADS == 4) ? (j < 4) : (j == 0);
      const float* av = (is_src ? as_ : ad_) + hh * C;
      const float* wb = W + hh * C;
#pragma unroll
      for (int t = 0; t < 8; ++t) {
        float s = 0.f;
        for (int c = 0; c < C; ++c) s = fmaf(wb[(size_t)(chunk * 8 + t) * BN + c], av[c], s);
        v[t] = s;
      }
    }
  }
  uint4 u;
  u.x = pack2(v[0], v[1]);
  u.y = pack2(v[2], v[3]);
  u.z = pack2(v[4], v[5]);
  u.w = pack2(v[6], v[7]);
  out[i] = u;
}

// Fused setup: blocks [0,9) prep W1; [9,14) prep W2; rest zero cnt.
__global__ void k_setup(const float* __restrict__ W1, const float* __restrict__ a1s,
                        const float* __restrict__ a1d, uint4* __restrict__ wsw1,
                        const float* __restrict__ W2, const float* __restrict__ a2s,
                        const float* __restrict__ a2d, uint4* __restrict__ wsw2,
                        int* __restrict__ cnt, int N) {
  const int b = blockIdx.x;
  const int tid = threadIdx.x;
  if (b < 9) {
    prep_w<128, 4>(W1, a1s, a1d, wsw1, b * 256 + tid);
  } else if (b < 14) {
    prep_w<64, 1>(W2, a2s, a2d, wsw2, (b - 9) * 256 + tid);
  } else {
    const int i = (b - 14) * 256 + tid;
    if (i < (N >> 2)) ((int4*)cnt)[i] = make_int4(0, 0, 0, 0);
    const int r = (N & ~3) + i;  // tail (N%4 elems)
    if (i < 4 && r < N) cnt[r] = 0;
  }
}

// ---- MFMA GEMM: h = x@W (bf16), logits from extra tile. Single reused LDS buf.
template <int BN, int HEADS>
__global__ __launch_bounds__(256) void k_mfma_gemm(
    const float* __restrict__ x, const uint4* __restrict__ wsw,
    __hip_bfloat16* __restrict__ h_out, float* __restrict__ als,
    float* __restrict__ ald, int N) {
  constexpr int XC = BN + 16;
  constexpr int NTILES = BN / 16;
  constexpr int BUFSZ = (XC * 256 > 128 * 256) ? XC * 256 : 128 * 256;
  __shared__ unsigned char buf[BUFSZ];
  const int tid = threadIdx.x;
  const int lane = tid & 63;
  const int wid = tid >> 6;
  const int base = blockIdx.x * 128;

  for (int it = 0; it < 8; ++it) {
    const int i = it * 256 + tid;
    const int r = i >> 4, c = i & 15;
    const int g = base + r;
    float4 f0 = make_float4(0.f, 0.f, 0.f, 0.f), f1 = f0;
    if (g < N) {
      const float* xp = x + (size_t)g * 128 + c * 8;
      f0 = *(const float4*)xp;
      f1 = *(const float4*)(xp + 4);
    }
    uint4 u;
    u.x = pack2(f0.x, f0.y);
    u.y = pack2(f0.z, f0.w);
    u.z = pack2(f1.x, f1.y);
    u.w = pack2(f1.z, f1.w);
    *(uint4*)(buf + r * 256 + ((c * 16) ^ ((r & 7) << 4))) = u;
  }
  __syncthreads();

  const int lg = lane >> 4;
  const int ll = lane & 15;
  union U { uint4 u; short8 s; };
  short8 afr[2][4];
#pragma unroll
  for (int rt = 0; rt < 2; ++rt) {
    const int row = wid * 32 + rt * 16 + ll;
    const unsigned char* rp = buf + row * 256;
    const int swz = (row & 7) << 4;
#pragma unroll
    for (int ks = 0; ks < 4; ++ks) {
      U t;
      t.u = *(const uint4*)(rp + ((ks * 64 + lg * 16) ^ swz));
      afr[rt][ks] = t.s;
    }
  }
  __syncthreads();  // done with X region; reuse buf for W

  {
    uint4* dst = (uint4*)buf;
    for (int i = tid; i < XC * 16; i += 256) dst[i] = wsw[i];
  }
  __syncthreads();

  f32x4 acc[2][NTILES + 1];
#pragma unroll
  for (int rt = 0; rt < 2; ++rt)
#pragma unroll
    for (int t = 0; t <= NTILES; ++t) acc[rt][t] = (f32x4){0.f, 0.f, 0.f, 0.f};

#pragma unroll
  for (int t = 0; t <= NTILES; ++t) {
    const int col = t * 16 + ll;
    const unsigned char* cp = buf + col * 256;
    const int swz = (col & 7) << 4;
#pragma unroll
    for (int ks = 0; ks < 4; ++ks) {
      U b;
      b.u = *(const uint4*)(cp + ((ks * 64 + lg * 16) ^ swz));
      acc[0][t] = __builtin_amdgcn_mfma_f32_16x16x32_bf16(afr[0][ks], b.s, acc[0][t], 0, 0, 0);
      acc[1][t] = __builtin_amdgcn_mfma_f32_16x16x32_bf16(afr[1][ks], b.s, acc[1][t], 0, 0, 0);
    }
  }

#pragma unroll
  for (int rt = 0; rt < 2; ++rt) {
#pragma unroll
    for (int r = 0; r < 4; ++r) {
      const int row = base + wid * 32 + rt * 16 + lg * 4 + r;
      if (row < N) {
        const float v = acc[rt][NTILES][r];
        if (HEADS == 4) {
          if (ll < 4) als[(size_t)row * 4 + ll] = v;
          else if (ll < 8) ald[(size_t)row * 4 + (ll - 4)] = v;
        } else {
          if (ll == 0) als[row] = v;
          else if (ll == 1) ald[row] = v;
        }
      }
    }
  }

  __syncthreads();
#pragma unroll
  for (int rt = 0; rt < 2; ++rt) {
#pragma unroll
    for (int t = 0; t < NTILES; ++t) {
#pragma unroll
      for (int r = 0; r < 4; ++r) {
        const float v = acc[rt][t][r];
        const float vn = __shfl_xor(v, 1, 64);
        if (!(lane & 1)) {
          const int row = wid * 32 + rt * 16 + lg * 4 + r;
          *(unsigned*)(buf + row * (BN * 2) + (t * 16 + ll) * 2) = pack2(v, vn);
        }
      }
    }
  }
  __syncthreads();
  {
    constexpr int U4 = 128 * BN / 8;
    constexpr int U4R = BN / 8;
    for (int i = tid; i < U4; i += 256) {
      const int row = i / U4R;
      const int g = base + row;
      if (g < N)
        *(uint4*)((unsigned short*)h_out + (size_t)g * BN + (i % U4R) * 8) = ((uint4*)buf)[i];
    }
  }
}

// ---------------- CSR build (counting sort by dst) ----------------
__global__ void k_count(const int* __restrict__ edst, int* __restrict__ cnt, int E) {
  int i = blockIdx.x * blockDim.x + threadIdx.x;
  if (i < E) atomicAdd(cnt + edst[i], 1);
}

// +1 folded in (self-loop); cnt zeroed in k_setup.
__global__ void k_scan_local(const int* __restrict__ cnt, int* __restrict__ rowptr,
                             int* __restrict__ bsum, int N) {
  __shared__ int lds[256];
  const int tid = threadIdx.x;
  const int base = blockIdx.x * 1024;
  int vals[4], tsum = 0;
#pragma unroll
  for (int q = 0; q < 4; ++q) {
    int i = base + tid * 4 + q;
    vals[q] = (i < N) ? cnt[i] + 1 : 0;
    tsum += vals[q];
  }
  lds[tid] = tsum;
  __syncthreads();
  for (int off = 1; off < 256; off <<= 1) {
    int t = (tid >= off) ? lds[tid - off] : 0;
    __syncthreads();
    lds[tid] += t;
    __syncthreads();
  }
  int run = lds[tid] - tsum;
  if (tid == 255) bsum[blockIdx.x] = lds[255];
#pragma unroll
  for (int q = 0; q < 4; ++q) {
    int i = base + tid * 4 + q;
    if (i < N) rowptr[i] = run;
    run += vals[q];
  }
}

// Fused bsum-scan + add: every block redundantly scans bsum (<=128 entries) in
// LDS, then applies its exclusive prefix.
__global__ void k_scan_add2(const int* __restrict__ bsum, int nb,
                            int* __restrict__ rowptr, int* __restrict__ cursor,
                            int N, int total) {
  __shared__ int pref[128];
  const int tid = threadIdx.x;
  int own = 0;
  if (tid < 128) {
    own = (tid < nb) ? bsum[tid] : 0;
    pref[tid] = own;
  }
  __syncthreads();
  for (int off = 1; off < 128; off <<= 1) {
    int t = (tid >= off && tid < 128) ? pref[tid - off] : 0;
    __syncthreads();
    if (tid < 128) pref[tid] += t;
    __syncthreads();
  }
  if (tid < 128) pref[tid] -= own;  // exclusive
  __syncthreads();
  const int i = blockIdx.x * blockDim.x + tid;
  if (i < N) {
    int r = rowptr[i] + pref[i >> 10];
    rowptr[i] = r;
    cursor[i] = r;
  } else if (i == N) {
    rowptr[N] = total;
  }
}

// Partitioned CSR fill: 4 parts (bid&3 -> parts owned by 2 XCDs each; measured
// best in R10/R11; NPARTS=2 regressed via cross-XCD line ping-pong).
__global__ void k_build_part(const int* __restrict__ esrc, const int* __restrict__ edst,
                             int* __restrict__ cursor, int* __restrict__ nbr, int E, int N) {
  constexpr int NPARTS = 4;
  const int p = blockIdx.x & 3;
  const int span = (N + NPARTS - 1) / NPARTS;
  const int lo = p * span;
  const int hi = min(N, lo + span);
  const int gid = (int)(blockIdx.x >> 2) * blockDim.x + threadIdx.x;
  const int stride = (int)(gridDim.x >> 2) * blockDim.x;
  const int E4 = E >> 2;
  for (int i = gid; i < E4; i += stride) {
    const int4 d4 = ((const int4*)edst)[i];
    const int4 s4 = ((const int4*)esrc)[i];
    if (d4.x >= lo && d4.x < hi) nbr[atomicAdd(cursor + d4.x, 1)] = s4.x;
    if (d4.y >= lo && d4.y < hi) nbr[atomicAdd(cursor + d4.y, 1)] = s4.y;
    if (d4.z >= lo && d4.z < hi) nbr[atomicAdd(cursor + d4.z, 1)] = s4.z;
    if (d4.w >= lo && d4.w < hi) nbr[atomicAdd(cursor + d4.w, 1)] = s4.w;
  }
  for (int i = E4 * 4 + gid; i < E + N; i += stride) {
    const int d = i < E ? edst[i] : i - E;
    if (d >= lo && d < hi) {
      const int sn = i < E ? esrc[i] : i - E;
      nbr[atomicAdd(cursor + d, 1)] = sn;
    }
  }
}

// ---------------- Gather layer 1: H=4, C=32; two nodes/wave; 8-edge batches ----
__global__ void k_gather_l1(const int* __restrict__ rowptr, const int* __restrict__ nbr,
                            const float* __restrict__ als, const float* __restrict__ ald,
                            const __hip_bfloat16* __restrict__ hfeat,
                            const float* __restrict__ bias,
                            float* __restrict__ out, int N) {
  __shared__ float atab[4][2][4][40];    // [wave][half][head][edge]
  __shared__ unsigned otab[4][2][32];    // [wave][half][edge] byte offsets
  const int lane = threadIdx.x & 63;
  const int wid = threadIdx.x >> 6;
  const int half = lane >> 5;
  const int l32 = lane & 31;
  const int node = (int)((blockIdx.x * blockDim.x + threadIdx.x) >> 6) * 2 + half;
  const bool valid = node < N;
  int start = 0, end = 0;
  if (valid) {
    start = rowptr[node];
    end = rowptr[node + 1];
  }
  const int deg = end - start;
  const float4 aldd = valid ? ((const float4*)ald)[node] : make_float4(0.f, 0.f, 0.f, 0.f);

  float t[4];
  int myn = 0;
  {
    const int j = start + l32;
    if (j < end) {
      myn = nbr[j];
      const float4 av = ((const float4*)als)[myn];
      const float tr[4] = {av.x + aldd.x, av.y + aldd.y, av.z + aldd.z, av.w + aldd.w};
#pragma unroll
      for (int h = 0; h < 4; ++h) t[h] = tr[h] >= 0.f ? tr[h] : NEG_SLOPE * tr[h];
    } else {
#pragma unroll
      for (int h = 0; h < 4; ++h) t[h] = NEG_BIG;
    }
  }
  otab[wid][half][l32] = (unsigned)myn << 8;  // 256B rows

  float Mh[4], rden[4], myex[4];
  if (deg <= 32) {
#pragma unroll
    for (int h = 0; h < 4; ++h) {
      float M = t[h];
#pragma unroll
      for (int off = 1; off < 32; off <<= 1) M = fmaxf(M, __shfl_xor(M, off, 64));
      const float e = __expf(t[h] - M);
      float sum = e;
#pragma unroll
      for (int off = 1; off < 32; off <<= 1) sum += __shfl_xor(sum, off, 64);
      Mh[h] = M;
      rden[h] = 1.f / sum;
      myex[h] = e * rden[h];
    }
  } else {
    float m[4], s[4];
#pragma unroll
    for (int h = 0; h < 4; ++h) {
      m[h] = t[h];
      s[h] = (t[h] > NEG_BIG) ? 1.f : 0.f;
    }
    for (int b = start + 32; b < end; b += 32) {
      const int j = b + l32;
      if (j < end) {
        const int sn = nbr[j];
        const float4 av = ((const float4*)als)[sn];
        const float tr[4] = {av.x + aldd.x, av.y + aldd.y, av.z + aldd.z, av.w + aldd.w};
#pragma unroll
        for (int h = 0; h < 4; ++h) {
          const float tv = tr[h] >= 0.f ? tr[h] : NEG_SLOPE * tr[h];
          const float M = fmaxf(m[h], tv);
          s[h] = s[h] * __expf(m[h] - M) + __expf(tv - M);
          m[h] = M;
        }
      }
    }
#pragma unroll
    for (int h = 0; h < 4; ++h) {
      float M = m[h];
#pragma unroll
      for (int off = 1; off < 32; off <<= 1) M = fmaxf(M, __shfl_xor(M, off, 64));
      float e = s[h] * __expf(m[h] - M);
#pragma unroll
      for (int off = 1; off < 32; off <<= 1) e += __shfl_xor(e, off, 64);
      Mh[h] = M;
      rden[h] = 1.f / e;
      myex[h] = __expf(t[h] - M) * rden[h];
    }
  }
#pragma unroll
  for (int h = 0; h < 4; ++h) atab[wid][half][h][l32] = myex[h];

  // pass C: 8 edges per iteration (2 slots x 4 batched loads in flight)
  const int sub = l32 >> 4;
  const int q = l32 & 15;
  const int head = q >> 2;
  const char* hq = (const char*)hfeat + q * 16;
  float acc[8];
#pragma unroll
  for (int k = 0; k < 8; ++k) acc[k] = 0.f;

  const int nq = deg < 32 ? deg : 32;
  const float* ap = &atab[wid][half][head][0];
  const unsigned* op = &otab[wid][half][0];
  for (int j0 = 0; j0 < nq; j0 += 8) {
    const float a0 = ap[j0 + sub];
    const float a1 = ap[j0 + 2 + sub];
    const float a2 = ap[j0 + 4 + sub];
    const float a3 = ap[j0 + 6 + sub];
    const uint4 v0 = *(const uint4*)(hq + op[j0 + sub]);
    const uint4 v1 = *(const uint4*)(hq + op[j0 + 2 + sub]);
    const uint4 v2 = *(const uint4*)(hq + op[j0 + 4 + sub]);
    const uint4 v3 = *(const uint4*)(hq + op[j0 + 6 + sub]);
    FMA8R(v0, a0);
    FMA8R(v1, a1);
    FMA8R(v2, a2);
    FMA8R(v3, a3);
  }
  if (deg > 32) {
    const float Mm = head == 0 ? Mh[0] : head == 1 ? Mh[1] : head == 2 ? Mh[2] : Mh[3];
    const float rd = head == 0 ? rden[0] : head == 1 ? rden[1] : head == 2 ? rden[2] : rden[3];
    const float ad_ = head == 0 ? aldd.x : head == 1 ? aldd.y : head == 2 ? aldd.z : aldd.w;
    for (int j0 = 32; j0 < deg; j0 += 2) {
      const int j = j0 + sub;
      float a = 0.f;
      int sn = 0;
      if (j < deg) {
        sn = nbr[start + j];
        const float4 av = ((const float4*)als)[sn];
        const float as_ = head == 0 ? av.x : head == 1 ? av.y : head == 2 ? av.z : av.w;
        float tv = as_ + ad_;
        tv = tv >= 0.f ? tv : NEG_SLOPE * tv;
        a = __expf(tv - Mm) * rd;
      }
      const uint4 v = *(const uint4*)(hq + (size_t)sn * 256);
      FMA8R(v, a);
    }
  }

#pragma unroll
  for (int k = 0; k < 8; ++k) acc[k] += __shfl_xor(acc[k], 16, 64);
  if (valid && sub == 0) {
    const float4 b0 = ((const float4*)bias)[q * 2];
    const float4 b1 = ((const float4*)bias)[q * 2 + 1];
    float r[8] = {acc[0] + b0.x, acc[1] + b0.y, acc[2] + b0.z, acc[3] + b0.w,
                  acc[4] + b1.x, acc[5] + b1.y, acc[6] + b1.z, acc[7] + b1.w};
#pragma unroll
    for (int k = 0; k < 8; ++k) r[k] = r[k] > 0.f ? r[k] : __expf(r[k]) - 1.f;
    float4* opo = (float4*)(out + (size_t)node * 128 + q * 8);
    opo[0] = make_float4(r[0], r[1], r[2], r[3]);
    opo[1] = make_float4(r[4], r[5], r[6], r[7]);
  }
}

// ---------------- Gather layer 2: H=1, C=64; two nodes/wave; 16-edge batches ----
__global__ void k_gather_l2(const int* __restrict__ rowptr, const int* __restrict__ nbr,
                            const float* __restrict__ als, const float* __restrict__ ald,
                            const __hip_bfloat16* __restrict__ hfeat,
                            const float* __restrict__ bias,
                            float* __restrict__ out, int N) {
  __shared__ float2 atab[4][2][36];  // {alpha, off}
  const int lane = threadIdx.x & 63;
  const int wid = threadIdx.x >> 6;
  const int half = lane >> 5;
  const int l32 = lane & 31;
  const int node = (int)((blockIdx.x * blockDim.x + threadIdx.x) >> 6) * 2 + half;
  const bool valid = node < N;
  int start = 0, end = 0;
  if (valid) {
    start = rowptr[node];
    end = rowptr[node + 1];
  }
  const int deg = end - start;
  const float ald0 = valid ? ald[node] : 0.f;

  float t = NEG_BIG;
  int myn = 0;
  {
    const int j = start + l32;
    if (j < end) {
      myn = nbr[j];
      float tv = als[myn] + ald0;
      t = tv >= 0.f ? tv : NEG_SLOPE * tv;
    }
  }

  float M, rden, myal;
  if (deg <= 32) {
    M = t;
#pragma unroll
    for (int off = 1; off < 32; off <<= 1) M = fmaxf(M, __shfl_xor(M, off, 64));
    const float e = __expf(t - M);
    float sum = e;
#pragma unroll
    for (int off = 1; off < 32; off <<= 1) sum += __shfl_xor(sum, off, 64);
    rden = 1.f / sum;
    myal = e * rden;
  } else {
    float m = t, s = (t > NEG_BIG) ? 1.f : 0.f;
    for (int b = start + 32; b < end; b += 32) {
      const int j = b + l32;
      if (j < end) {
        float tv = als[nbr[j]] + ald0;
        tv = tv >= 0.f ? tv : NEG_SLOPE * tv;
        const float Mn = fmaxf(m, tv);
        s = s * __expf(m - Mn) + __expf(tv - Mn);
        m = Mn;
      }
    }
    M = m;
#pragma unroll
    for (int off = 1; off < 32; off <<= 1) M = fmaxf(M, __shfl_xor(M, off, 64));
    float e = s * __expf(m - M);
#pragma unroll
    for (int off = 1; off < 32; off <<= 1) e += __shfl_xor(e, off, 64);
    rden = 1.f / e;
    myal = __expf(t - M) * rden;
  }
  atab[wid][half][l32] = make_float2(myal, __int_as_float(myn << 7));  // 128B rows

  const int sub = l32 >> 3;  // 4 edge slots
  const int q = l32 & 7;
  const char* hq = (const char*)hfeat + q * 16;
  float acc[8];
#pragma unroll
  for (int k = 0; k < 8; ++k) acc[k] = 0.f;

  const int nq = deg < 32 ? deg : 32;
  const float2* ap = &atab[wid][half][0];
  for (int j0 = 0; j0 < nq; j0 += 16) {
    const float2 o0 = ap[j0 + sub];
    const float2 o1 = ap[j0 + 4 + sub];
    const float2 o2 = ap[j0 + 8 + sub];
    const float2 o3 = ap[j0 + 12 + sub];
    const uint4 v0 = *(const uint4*)(hq + (unsigned)__float_as_int(o0.y));
    const uint4 v1 = *(const uint4*)(hq + (unsigned)__float_as_int(o1.y));
    const uint4 v2 = *(const uint4*)(hq + (unsigned)__float_as_int(o2.y));
    const uint4 v3 = *(const uint4*)(hq + (unsigned)__float_as_int(o3.y));
    FMA8(v0, o0.x);
    FMA8(v1, o1.x);
    FMA8(v2, o2.x);
    FMA8(v3, o3.x);
  }
  if (deg > 32) {
    for (int j0 = 32; j0 < deg; j0 += 4) {
      const int j = j0 + sub;
      float a = 0.f;
      int sn = 0;
      if (j < deg) {
        sn = nbr[start + j];
        float tv = als[sn] + ald0;
        tv = tv >= 0.f ? tv : NEG_SLOPE * tv;
        a = __expf(tv - M) * rden;
      }
      const uint4 v = *(const uint4*)(hq + (size_t)sn * 128);
      FMA8(v, a);
    }
  }

#pragma unroll
  for (int k = 0; k < 8; ++k) {
    acc[k] += __shfl_xor(acc[k], 8, 64);
    acc[k] += __shfl_xor(acc[k], 16, 64);
  }
  if (valid && sub == 0) {
    const float4 b0 = ((const float4*)bias)[q * 2];
    const float4 b1 = ((const float4*)bias)[q * 2 + 1];
    float4* opo = (float4*)(out + (size_t)node * 64 + q * 8);
    opo[0] = make_float4(acc[0] + b0.x, acc[1] + b0.y, acc[2] + b0.z, acc[3] + b0.w);
    opo[1] = make_float4(acc[4] + b1.x, acc[5] + b1.y, acc[6] + b1.z, acc[7] + b1.w);
  }
}

extern "C" void kernel_launch(void* const* d_in, const int* in_sizes, int n_in,
                              void* d_out, int out_size, void* d_ws, size_t ws_size,
                              hipStream_t stream) {
  const float* x   = (const float*)d_in[0];
  const int*   ei  = (const int*)d_in[1];
  const float* W1  = (const float*)d_in[2];
  const float* a1s = (const float*)d_in[3];
  const float* a1d = (const float*)d_in[4];
  const float* b1  = (const float*)d_in[5];
  const float* W2  = (const float*)d_in[6];
  const float* a2s = (const float*)d_in[7];
  const float* a2d = (const float*)d_in[8];
  const float* b2  = (const float*)d_in[9];

  const int N = in_sizes[0] / 128;  // 100000
  const int E = in_sizes[1] / 2;    // 1600000
  const int* esrc = ei;
  const int* edst = ei + E;

  float* ws   = (float*)d_ws;
  __hip_bfloat16* h = (__hip_bfloat16*)ws;   // N*128 bf16 (slot sized N*128 f32)
  float* out1 = ws   + (size_t)N * 128;      // N*128 f32
  float* als  = out1 + (size_t)N * 128;      // N*4
  float* ald  = als  + (size_t)N * 4;        // N*4
  int* cnt    = (int*)(ald + (size_t)N * 4); // N
  int* rowptr = cnt + N;                     // N+1
  int* cursor = rowptr + N + 1;              // N
  int* bsum   = cursor + N;                  // 1024
  int* nbr    = bsum + 1024;                 // E+N
  size_t off = ((size_t)((nbr + E + N) - (int*)ws) + 3) & ~(size_t)3;
  uint4* wsw1 = (uint4*)((int*)ws + off);    // 144*16 uint4
  uint4* wsw2 = wsw1 + 144 * 16;             // 80*16 uint4

  float* outF = (float*)d_out;               // N*64

  const int total = E + N;
  const int nb = (N + 1023) / 1024;

  // ---- setup (W preps + cnt zero) + CSR build ----
  const int zb = ((N >> 2) + 255) / 256;
  k_setup<<<14 + zb, 256, 0, stream>>>(W1, a1s, a1d, wsw1, W2, a2s, a2d, wsw2, cnt, N);
  k_count<<<(E + 255) / 256, 256, 0, stream>>>(edst, cnt, E);
  k_scan_local<<<nb, 256, 0, stream>>>(cnt, rowptr, bsum, N);
  k_scan_add2<<<(N + 256) / 256, 256, 0, stream>>>(bsum, nb, rowptr, cursor, N, total);
  k_build_part<<<1280, 256, 0, stream>>>(esrc, edst, cursor, nbr, E, N);

  // ---- Layer 1: H=4, C=32, concat -> [N,128], +b1, ELU ----
  k_mfma_gemm<128, 4><<<(N + 127) / 128, 256, 0, stream>>>(x, wsw1, h, als, ald, N);
  k_gather_l1<<<(N + 7) / 8, 256, 0, stream>>>(rowptr, nbr, als, ald, h, b1, out1, N);

  // ---- Layer 2: H=1, C=64, mean(H=1) -> [N,64], +b2 ----
  k_mfma_gemm<64, 1><<<(N + 127) / 128, 256, 0, stream>>>(out1, wsw2, h, als, ald, N);
  k_gather_l2<<<(N + 7) / 8, 256, 0, stream>>>(rowptr, nbr, als, ald, h, b2, outF, N);
}

// Round 14
// 300.358 us; speedup vs baseline: 1.1589x; 1.0667x over previous
//
#include <hip/hip_runtime.h>
#include <hip/hip_bf16.h>
#include <math.h>

static constexpr float NEG_SLOPE = 0.2f;
static constexpr float NEG_BIG = -3.0e38f;  // finite sentinel: avoids (-inf)-(-inf)=NaN

typedef __attribute__((ext_vector_type(8))) short short8;  // 8 bf16 (4 VGPRs)
typedef __attribute__((ext_vector_type(4))) float f32x4;
typedef __attribute__((ext_vector_type(4))) int i32x4;

__device__ __forceinline__ float blo(unsigned u) { return __uint_as_float(u << 16); }
__device__ __forceinline__ float bhi(unsigned u) { return __uint_as_float(u & 0xffff0000u); }
// hi bf16 read WITHOUT masking: low 16 bits are <=2^-8 relative mantissa noise.
__device__ __forceinline__ float bhiraw(unsigned u) { return __uint_as_float(u); }
__device__ __forceinline__ unsigned pack2(float a, float b) {
  __hip_bfloat162 t = __float22bfloat162_rn(make_float2(a, b));
  union { __hip_bfloat162 b; unsigned u; } v;
  v.b = t;
  return v.u;
}
// streaming (non-temporal) int4 load: avoids evicting L2-resident write regions
__device__ __forceinline__ i32x4 ntload4(const int* p) {
  return __builtin_nontemporal_load((const i32x4*)p);
}

#define FMA8(V, A)                         \
  acc[0] = fmaf(blo((V).x), (A), acc[0]);  \
  acc[1] = fmaf(bhi((V).x), (A), acc[1]);  \
  acc[2] = fmaf(blo((V).y), (A), acc[2]);  \
  acc[3] = fmaf(bhi((V).y), (A), acc[3]);  \
  acc[4] = fmaf(blo((V).z), (A), acc[4]);  \
  acc[5] = fmaf(bhi((V).z), (A), acc[5]);  \
  acc[6] = fmaf(blo((V).w), (A), acc[6]);  \
  acc[7] = fmaf(bhi((V).w), (A), acc[7])

#define FMA8R(V, A)                           \
  acc[0] = fmaf(blo((V).x), (A), acc[0]);     \
  acc[1] = fmaf(bhiraw((V).x), (A), acc[1]);  \
  acc[2] = fmaf(blo((V).y), (A), acc[2]);     \
  acc[3] = fmaf(bhiraw((V).y), (A), acc[3]);  \
  acc[4] = fmaf(blo((V).z), (A), acc[4]);     \
  acc[5] = fmaf(bhiraw((V).z), (A), acc[5]);  \
  acc[6] = fmaf(blo((V).w), (A), acc[6]);     \
  acc[7] = fmaf(bhiraw((V).w), (A), acc[7])

// ---- W prep (device fn): fp32 [k][col] -> bf16 swizzled [col][k] image + 16
// extra cols of WA = W@A so the GEMM emits logits as a free tile.
template <int BN, int HEADS>
__device__ void prep_w(const float* __restrict__ W, const float* __restrict__ as_,
                       const float* __restrict__ ad_, uint4* __restrict__ out, int i) {
  constexpr int XC = BN + 16;
  constexpr int C = BN / HEADS;
  if (i >= XC * 16) return;
  const int col = i >> 4;
  const int chunk = (i & 15) ^ (col & 7);
  float v[8];
  if (col < BN) {
#pragma unroll
    for (int t = 0; t < 8; ++t) v[t] = W[(size_t)(chunk * 8 + t) * BN + col];
  } else {
    const int j = col - BN;
#pragma unroll
    for (int t = 0; t < 8; ++t) v[t] = 0.f;
    if (j < 2 * HEADS) {
      const int hh = (HEADS == 4) ? (j & 3) : 0;
      const bool is_src = (HEADS == 4) ? (j < 4) : (j == 0);
      const float* av = (is_src ? as_ : ad_) + hh * C;
      const float* wb = W + hh * C;
#pragma unroll
      for (int t = 0; t < 8; ++t) {
        float s = 0.f;
        for (int c = 0; c < C; ++c) s = fmaf(wb[(size_t)(chunk * 8 + t) * BN + c], av[c], s);
        v[t] = s;
      }
    }
  }
  uint4 u;
  u.x = pack2(v[0], v[1]);
  u.y = pack2(v[2], v[3]);
  u.z = pack2(v[4], v[5]);
  u.w = pack2(v[6], v[7]);
  out[i] = u;
}

// Fused setup: blocks [0,9) prep W1; [9,14) prep W2; rest zero cnt.
__global__ void k_setup(const float* __restrict__ W1, const float* __restrict__ a1s,
                        const float* __restrict__ a1d, uint4* __restrict__ wsw1,
                        const float* __restrict__ W2, const float* __restrict__ a2s,
                        const float* __restrict__ a2d, uint4* __restrict__ wsw2,
                        int* __restrict__ cnt, int N) {
  const int b = blockIdx.x;
  const int tid = threadIdx.x;
  if (b < 9) {
    prep_w<128, 4>(W1, a1s, a1d, wsw1, b * 256 + tid);
  } else if (b < 14) {
    prep_w<64, 1>(W2, a2s, a2d, wsw2, (b - 9) * 256 + tid);
  } else {
    const int i = (b - 14) * 256 + tid;
    if (i < (N >> 2)) ((int4*)cnt)[i] = make_int4(0, 0, 0, 0);
    const int r = (N & ~3) + i;  // tail (N%4 elems)
    if (i < 4 && r < N) cnt[r] = 0;
  }
}

// ---- MFMA GEMM body: h = x@W (bf16), logits from extra tile. Reused LDS buf.
template <int BN, int HEADS>
__device__ void gemm_body(const float* __restrict__ x, const uint4* __restrict__ wsw,
                          __hip_bfloat16* __restrict__ h_out, float* __restrict__ als,
                          float* __restrict__ ald, int N, int bid) {
  constexpr int XC = BN + 16;
  constexpr int NTILES = BN / 16;
  constexpr int BUFSZ = (XC * 256 > 128 * 256) ? XC * 256 : 128 * 256;
  __shared__ unsigned char buf[BUFSZ];
  const int tid = threadIdx.x;
  const int lane = tid & 63;
  const int wid = tid >> 6;
  const int base = bid * 128;

  for (int it = 0; it < 8; ++it) {
    const int i = it * 256 + tid;
    const int r = i >> 4, c = i & 15;
    const int g = base + r;
    float4 f0 = make_float4(0.f, 0.f, 0.f, 0.f), f1 = f0;
    if (g < N) {
      const float* xp = x + (size_t)g * 128 + c * 8;
      f0 = *(const float4*)xp;
      f1 = *(const float4*)(xp + 4);
    }
    uint4 u;
    u.x = pack2(f0.x, f0.y);
    u.y = pack2(f0.z, f0.w);
    u.z = pack2(f1.x, f1.y);
    u.w = pack2(f1.z, f1.w);
    *(uint4*)(buf + r * 256 + ((c * 16) ^ ((r & 7) << 4))) = u;
  }
  __syncthreads();

  const int lg = lane >> 4;
  const int ll = lane & 15;
  union U { uint4 u; short8 s; };
  short8 afr[2][4];
#pragma unroll
  for (int rt = 0; rt < 2; ++rt) {
    const int row = wid * 32 + rt * 16 + ll;
    const unsigned char* rp = buf + row * 256;
    const int swz = (row & 7) << 4;
#pragma unroll
    for (int ks = 0; ks < 4; ++ks) {
      U t;
      t.u = *(const uint4*)(rp + ((ks * 64 + lg * 16) ^ swz));
      afr[rt][ks] = t.s;
    }
  }
  __syncthreads();  // done with X region; reuse buf for W

  {
    uint4* dst = (uint4*)buf;
    for (int i = tid; i < XC * 16; i += 256) dst[i] = wsw[i];
  }
  __syncthreads();

  f32x4 acc[2][NTILES + 1];
#pragma unroll
  for (int rt = 0; rt < 2; ++rt)
#pragma unroll
    for (int t = 0; t <= NTILES; ++t) acc[rt][t] = (f32x4){0.f, 0.f, 0.f, 0.f};

#pragma unroll
  for (int t = 0; t <= NTILES; ++t) {
    const int col = t * 16 + ll;
    const unsigned char* cp = buf + col * 256;
    const int swz = (col & 7) << 4;
#pragma unroll
    for (int ks = 0; ks < 4; ++ks) {
      U b;
      b.u = *(const uint4*)(cp + ((ks * 64 + lg * 16) ^ swz));
      acc[0][t] = __builtin_amdgcn_mfma_f32_16x16x32_bf16(afr[0][ks], b.s, acc[0][t], 0, 0, 0);
      acc[1][t] = __builtin_amdgcn_mfma_f32_16x16x32_bf16(afr[1][ks], b.s, acc[1][t], 0, 0, 0);
    }
  }

#pragma unroll
  for (int rt = 0; rt < 2; ++rt) {
#pragma unroll
    for (int r = 0; r < 4; ++r) {
      const int row = base + wid * 32 + rt * 16 + lg * 4 + r;
      if (row < N) {
        const float v = acc[rt][NTILES][r];
        if (HEADS == 4) {
          if (ll < 4) als[(size_t)row * 4 + ll] = v;
          else if (ll < 8) ald[(size_t)row * 4 + (ll - 4)] = v;
        } else {
          if (ll == 0) als[row] = v;
          else if (ll == 1) ald[row] = v;
        }
      }
    }
  }

  __syncthreads();
#pragma unroll
  for (int rt = 0; rt < 2; ++rt) {
#pragma unroll
    for (int t = 0; t < NTILES; ++t) {
#pragma unroll
      for (int r = 0; r < 4; ++r) {
        const float v = acc[rt][t][r];
        const float vn = __shfl_xor(v, 1, 64);
        if (!(lane & 1)) {
          const int row = wid * 32 + rt * 16 + lg * 4 + r;
          *(unsigned*)(buf + row * (BN * 2) + (t * 16 + ll) * 2) = pack2(v, vn);
        }
      }
    }
  }
  __syncthreads();
  {
    constexpr int U4 = 128 * BN / 8;
    constexpr int U4R = BN / 8;
    for (int i = tid; i < U4; i += 256) {
      const int row = i / U4R;
      const int g = base + row;
      if (g < N)
        *(uint4*)((unsigned short*)h_out + (size_t)g * BN + (i % U4R) * 8) = ((uint4*)buf)[i];
    }
  }
}

template <int BN, int HEADS>
__global__ __launch_bounds__(256) void k_mfma_gemm(
    const float* __restrict__ x, const uint4* __restrict__ wsw,
    __hip_bfloat16* __restrict__ h_out, float* __restrict__ als,
    float* __restrict__ ald, int N) {
  gemm_body<BN, HEADS>(x, wsw, h_out, als, ald, N, blockIdx.x);
}

// ---- CSR build body: 4 parts (bid&3), nt edge reads ----
__device__ void build_body(const int* __restrict__ esrc, const int* __restrict__ edst,
                           int* __restrict__ cursor, int* __restrict__ nbr, int E, int N,
                           int bid, int nbuild) {
  constexpr int NPARTS = 4;
  const int p = bid & 3;
  const int span = (N + NPARTS - 1) / NPARTS;
  const int lo = p * span;
  const int hi = min(N, lo + span);
  const int gid = (bid >> 2) * 256 + (int)threadIdx.x;
  const int stride = (nbuild >> 2) * 256;
  const int E4 = E >> 2;
  for (int i = gid; i < E4; i += stride) {
    const i32x4 d4 = ntload4(edst + i * 4);
    const i32x4 s4 = ntload4(esrc + i * 4);
    if (d4.x >= lo && d4.x < hi) nbr[atomicAdd(cursor + d4.x, 1)] = s4.x;
    if (d4.y >= lo && d4.y < hi) nbr[atomicAdd(cursor + d4.y, 1)] = s4.y;
    if (d4.z >= lo && d4.z < hi) nbr[atomicAdd(cursor + d4.z, 1)] = s4.z;
    if (d4.w >= lo && d4.w < hi) nbr[atomicAdd(cursor + d4.w, 1)] = s4.w;
  }
  for (int i = E4 * 4 + gid; i < E + N; i += stride) {
    const int d = i < E ? edst[i] : i - E;
    if (d >= lo && d < hi) {
      const int sn = i < E ? esrc[i] : i - E;
      nbr[atomicAdd(cursor + d, 1)] = sn;
    }
  }
}

// Fused: blocks [0,nbuild) build the CSR; blocks [nbuild,..) run layer-1 GEMM.
// Independent work -> memory-bound build overlaps compute-bound MFMA GEMM.
__global__ __launch_bounds__(256) void k_build_gemm1(
    const int* __restrict__ esrc, const int* __restrict__ edst,
    int* __restrict__ cursor, int* __restrict__ nbr, int E, int nbuild,
    const float* __restrict__ x, const uint4* __restrict__ wsw,
    __hip_bfloat16* __restrict__ h_out, float* __restrict__ als,
    float* __restrict__ ald, int N) {
  const int b = (int)blockIdx.x;
  if (b < nbuild) {
    build_body(esrc, edst, cursor, nbr, E, N, b, nbuild);
    return;
  }
  gemm_body<128, 4>(x, wsw, h_out, als, ald, N, b - nbuild);
}

// ---------------- CSR count / scan ----------------
__global__ void k_count(const int* __restrict__ edst, int* __restrict__ cnt, int E) {
  int i = blockIdx.x * blockDim.x + threadIdx.x;
  const int E4 = E >> 2;
  if (i < E4) {
    const i32x4 d4 = ntload4(edst + i * 4);
    atomicAdd(cnt + d4.x, 1);
    atomicAdd(cnt + d4.y, 1);
    atomicAdd(cnt + d4.z, 1);
    atomicAdd(cnt + d4.w, 1);
  } else {
    const int r = E4 * 4 + (i - E4);
    if (r < E) atomicAdd(cnt + edst[r], 1);
  }
}

// +1 folded in (self-loop); cnt zeroed in k_setup.
__global__ void k_scan_local(const int* __restrict__ cnt, int* __restrict__ rowptr,
                             int* __restrict__ bsum, int N) {
  __shared__ int lds[256];
  const int tid = threadIdx.x;
  const int base = blockIdx.x * 1024;
  int vals[4], tsum = 0;
#pragma unroll
  for (int q = 0; q < 4; ++q) {
    int i = base + tid * 4 + q;
    vals[q] = (i < N) ? cnt[i] + 1 : 0;
    tsum += vals[q];
  }
  lds[tid] = tsum;
  __syncthreads();
  for (int off = 1; off < 256; off <<= 1) {
    int t = (tid >= off) ? lds[tid - off] : 0;
    __syncthreads();
    lds[tid] += t;
    __syncthreads();
  }
  int run = lds[tid] - tsum;
  if (tid == 255) bsum[blockIdx.x] = lds[255];
#pragma unroll
  for (int q = 0; q < 4; ++q) {
    int i = base + tid * 4 + q;
    if (i < N) rowptr[i] = run;
    run += vals[q];
  }
}

// Fused bsum-scan + add: every block redundantly scans bsum (<=128 entries).
__global__ void k_scan_add2(const int* __restrict__ bsum, int nb,
                            int* __restrict__ rowptr, int* __restrict__ cursor,
                            int N, int total) {
  __shared__ int pref[128];
  const int tid = threadIdx.x;
  int own = 0;
  if (tid < 128) {
    own = (tid < nb) ? bsum[tid] : 0;
    pref[tid] = own;
  }
  __syncthreads();
  for (int off = 1; off < 128; off <<= 1) {
    int t = (tid >= off && tid < 128) ? pref[tid - off] : 0;
    __syncthreads();
    if (tid < 128) pref[tid] += t;
    __syncthreads();
  }
  if (tid < 128) pref[tid] -= own;  // exclusive
  __syncthreads();
  const int i = blockIdx.x * blockDim.x + tid;
  if (i < N) {
    int r = rowptr[i] + pref[i >> 10];
    rowptr[i] = r;
    cursor[i] = r;
  } else if (i == N) {
    rowptr[N] = total;
  }
}

// ---------------- Gather layer 1: H=4, C=32; two nodes/wave; 8-edge batches ----
__global__ void k_gather_l1(const int* __restrict__ rowptr, const int* __restrict__ nbr,
                            const float* __restrict__ als, const float* __restrict__ ald,
                            const __hip_bfloat16* __restrict__ hfeat,
                            const float* __restrict__ bias,
                            float* __restrict__ out, int N) {
  __shared__ float atab[4][2][4][40];    // [wave][half][head][edge]
  __shared__ unsigned otab[4][2][32];    // [wave][half][edge] byte offsets
  const int lane = threadIdx.x & 63;
  const int wid = threadIdx.x >> 6;
  const int half = lane >> 5;
  const int l32 = lane & 31;
  const int node = (int)((blockIdx.x * blockDim.x + threadIdx.x) >> 6) * 2 + half;
  const bool valid = node < N;
  int start = 0, end = 0;
  if (valid) {
    start = rowptr[node];
    end = rowptr[node + 1];
  }
  const int deg = end - start;
  const float4 aldd = valid ? ((const float4*)ald)[node] : make_float4(0.f, 0.f, 0.f, 0.f);

  float t[4];
  int myn = 0;
  {
    const int j = start + l32;
    if (j < end) {
      myn = nbr[j];
      const float4 av = ((const float4*)als)[myn];
      const float tr[4] = {av.x + aldd.x, av.y + aldd.y, av.z + aldd.z, av.w + aldd.w};
#pragma unroll
      for (int h = 0; h < 4; ++h) t[h] = tr[h] >= 0.f ? tr[h] : NEG_SLOPE * tr[h];
    } else {
#pragma unroll
      for (int h = 0; h < 4; ++h) t[h] = NEG_BIG;
    }
  }
  otab[wid][half][l32] = (unsigned)myn << 8;  // 256B rows

  float Mh[4], rden[4], myex[4];
  if (deg <= 32) {
#pragma unroll
    for (int h = 0; h < 4; ++h) {
      float M = t[h];
#pragma unroll
      for (int off = 1; off < 32; off <<= 1) M = fmaxf(M, __shfl_xor(M, off, 64));
      const float e = __expf(t[h] - M);
      float sum = e;
#pragma unroll
      for (int off = 1; off < 32; off <<= 1) sum += __shfl_xor(sum, off, 64);
      Mh[h] = M;
      rden[h] = 1.f / sum;
      myex[h] = e * rden[h];
    }
  } else {
    float m[4], s[4];
#pragma unroll
    for (int h = 0; h < 4; ++h) {
      m[h] = t[h];
      s[h] = (t[h] > NEG_BIG) ? 1.f : 0.f;
    }
    for (int b = start + 32; b < end; b += 32) {
      const int j = b + l32;
      if (j < end) {
        const int sn = nbr[j];
        const float4 av = ((const float4*)als)[sn];
        const float tr[4] = {av.x + aldd.x, av.y + aldd.y, av.z + aldd.z, av.w + aldd.w};
#pragma unroll
        for (int h = 0; h < 4; ++h) {
          const float tv = tr[h] >= 0.f ? tr[h] : NEG_SLOPE * tr[h];
          const float M = fmaxf(m[h], tv);
          s[h] = s[h] * __expf(m[h] - M) + __expf(tv - M);
          m[h] = M;
        }
      }
    }
#pragma unroll
    for (int h = 0; h < 4; ++h) {
      float M = m[h];
#pragma unroll
      for (int off = 1; off < 32; off <<= 1) M = fmaxf(M, __shfl_xor(M, off, 64));
      float e = s[h] * __expf(m[h] - M);
#pragma unroll
      for (int off = 1; off < 32; off <<= 1) e += __shfl_xor(e, off, 64);
      Mh[h] = M;
      rden[h] = 1.f / e;
      myex[h] = __expf(t[h] - M) * rden[h];
    }
  }
#pragma unroll
  for (int h = 0; h < 4; ++h) atab[wid][half][h][l32] = myex[h];

  // pass C: 8 edges per iteration (2 slots x 4 batched loads in flight)
  const int sub = l32 >> 4;
  const int q = l32 & 15;
  const int head = q >> 2;
  const char* hq = (const char*)hfeat + q * 16;
  float acc[8];
#pragma unroll
  for (int k = 0; k < 8; ++k) acc[k] = 0.f;

  const int nq = deg < 32 ? deg : 32;
  const float* ap = &atab[wid][half][head][0];
  const unsigned* op = &otab[wid][half][0];
  for (int j0 = 0; j0 < nq; j0 += 8) {
    const float a0 = ap[j0 + sub];
    const float a1 = ap[j0 + 2 + sub];
    const float a2 = ap[j0 + 4 + sub];
    const float a3 = ap[j0 + 6 + sub];
    const uint4 v0 = *(const uint4*)(hq + op[j0 + sub]);
    const uint4 v1 = *(const uint4*)(hq + op[j0 + 2 + sub]);
    const uint4 v2 = *(const uint4*)(hq + op[j0 + 4 + sub]);
    const uint4 v3 = *(const uint4*)(hq + op[j0 + 6 + sub]);
    FMA8R(v0, a0);
    FMA8R(v1, a1);
    FMA8R(v2, a2);
    FMA8R(v3, a3);
  }
  if (deg > 32) {
    const float Mm = head == 0 ? Mh[0] : head == 1 ? Mh[1] : head == 2 ? Mh[2] : Mh[3];
    const float rd = head == 0 ? rden[0] : head == 1 ? rden[1] : head == 2 ? rden[2] : rden[3];
    const float ad_ = head == 0 ? aldd.x : head == 1 ? aldd.y : head == 2 ? aldd.z : aldd.w;
    for (int j0 = 32; j0 < deg; j0 += 2) {
      const int j = j0 + sub;
      float a = 0.f;
      int sn = 0;
      if (j < deg) {
        sn = nbr[start + j];
        const float4 av = ((const float4*)als)[sn];
        const float as_ = head == 0 ? av.x : head == 1 ? av.y : head == 2 ? av.z : av.w;
        float tv = as_ + ad_;
        tv = tv >= 0.f ? tv : NEG_SLOPE * tv;
        a = __expf(tv - Mm) * rd;
      }
      const uint4 v = *(const uint4*)(hq + (size_t)sn * 256);
      FMA8R(v, a);
    }
  }

#pragma unroll
  for (int k = 0; k < 8; ++k) acc[k] += __shfl_xor(acc[k], 16, 64);
  if (valid && sub == 0) {
    const float4 b0 = ((const float4*)bias)[q * 2];
    const float4 b1 = ((const float4*)bias)[q * 2 + 1];
    float r[8] = {acc[0] + b0.x, acc[1] + b0.y, acc[2] + b0.z, acc[3] + b0.w,
                  acc[4] + b1.x, acc[5] + b1.y, acc[6] + b1.z, acc[7] + b1.w};
#pragma unroll
    for (int k = 0; k < 8; ++k) r[k] = r[k] > 0.f ? r[k] : __expf(r[k]) - 1.f;
    float4* opo = (float4*)(out + (size_t)node * 128 + q * 8);
    opo[0] = make_float4(r[0], r[1], r[2], r[3]);
    opo[1] = make_float4(r[4], r[5], r[6], r[7]);
  }
}

// ---------------- Gather layer 2: H=1, C=64; two nodes/wave; 16-edge batches ----
__global__ void k_gather_l2(const int* __restrict__ rowptr, const int* __restrict__ nbr,
                            const float* __restrict__ als, const float* __restrict__ ald,
                            const __hip_bfloat16* __restrict__ hfeat,
                            const float* __restrict__ bias,
                            float* __restrict__ out, int N) {
  __shared__ float2 atab[4][2][36];  // {alpha, off}
  const int lane = threadIdx.x & 63;
  const int wid = threadIdx.x >> 6;
  const int half = lane >> 5;
  const int l32 = lane & 31;
  const int node = (int)((blockIdx.x * blockDim.x + threadIdx.x) >> 6) * 2 + half;
  const bool valid = node < N;
  int start = 0, end = 0;
  if (valid) {
    start = rowptr[node];
    end = rowptr[node + 1];
  }
  const int deg = end - start;
  const float ald0 = valid ? ald[node] : 0.f;

  float t = NEG_BIG;
  int myn = 0;
  {
    const int j = start + l32;
    if (j < end) {
      myn = nbr[j];
      float tv = als[myn] + ald0;
      t = tv >= 0.f ? tv : NEG_SLOPE * tv;
    }
  }

  float M, rden, myal;
  if (deg <= 32) {
    M = t;
#pragma unroll
    for (int off = 1; off < 32; off <<= 1) M = fmaxf(M, __shfl_xor(M, off, 64));
    const float e = __expf(t - M);
    float sum = e;
#pragma unroll
    for (int off = 1; off < 32; off <<= 1) sum += __shfl_xor(sum, off, 64);
    rden = 1.f / sum;
    myal = e * rden;
  } else {
    float m = t, s = (t > NEG_BIG) ? 1.f : 0.f;
    for (int b = start + 32; b < end; b += 32) {
      const int j = b + l32;
      if (j < end) {
        float tv = als[nbr[j]] + ald0;
        tv = tv >= 0.f ? tv : NEG_SLOPE * tv;
        const float Mn = fmaxf(m, tv);
        s = s * __expf(m - Mn) + __expf(tv - Mn);
        m = Mn;
      }
    }
    M = m;
#pragma unroll
    for (int off = 1; off < 32; off <<= 1) M = fmaxf(M, __shfl_xor(M, off, 64));
    float e = s * __expf(m - M);
#pragma unroll
    for (int off = 1; off < 32; off <<= 1) e += __shfl_xor(e, off, 64);
    rden = 1.f / e;
    myal = __expf(t - M) * rden;
  }
  atab[wid][half][l32] = make_float2(myal, __int_as_float(myn << 7));  // 128B rows

  const int sub = l32 >> 3;  // 4 edge slots
  const int q = l32 & 7;
  const char* hq = (const char*)hfeat + q * 16;
  float acc[8];
#pragma unroll
  for (int k = 0; k < 8; ++k) acc[k] = 0.f;

  const int nq = deg < 32 ? deg : 32;
  const float2* ap = &atab[wid][half][0];
  for (int j0 = 0; j0 < nq; j0 += 16) {
    const float2 o0 = ap[j0 + sub];
    const float2 o1 = ap[j0 + 4 + sub];
    const float2 o2 = ap[j0 + 8 + sub];
    const float2 o3 = ap[j0 + 12 + sub];
    const uint4 v0 = *(const uint4*)(hq + (unsigned)__float_as_int(o0.y));
    const uint4 v1 = *(const uint4*)(hq + (unsigned)__float_as_int(o1.y));
    const uint4 v2 = *(const uint4*)(hq + (unsigned)__float_as_int(o2.y));
    const uint4 v3 = *(const uint4*)(hq + (unsigned)__float_as_int(o3.y));
    FMA8(v0, o0.x);
    FMA8(v1, o1.x);
    FMA8(v2, o2.x);
    FMA8(v3, o3.x);
  }
  if (deg > 32) {
    for (int j0 = 32; j0 < deg; j0 += 4) {
      const int j = j0 + sub;
      float a = 0.f;
      int sn = 0;
      if (j < deg) {
        sn = nbr[start + j];
        float tv = als[sn] + ald0;
        tv = tv >= 0.f ? tv : NEG_SLOPE * tv;
        a = __expf(tv - M) * rden;
      }
      const uint4 v = *(const uint4*)(hq + (size_t)sn * 128);
      FMA8(v, a);
    }
  }

#pragma unroll
  for (int k = 0; k < 8; ++k) {
    acc[k] += __shfl_xor(acc[k], 8, 64);
    acc[k] += __shfl_xor(acc[k], 16, 64);
  }
  if (valid && sub == 0) {
    const float4 b0 = ((const float4*)bias)[q * 2];
    const float4 b1 = ((const float4*)bias)[q * 2 + 1];
    float4* opo = (float4*)(out + (size_t)node * 64 + q * 8);
    opo[0] = make_float4(acc[0] + b0.x, acc[1] + b0.y, acc[2] + b0.z, acc[3] + b0.w);
    opo[1] = make_float4(acc[4] + b1.x, acc[5] + b1.y, acc[6] + b1.z, acc[7] + b1.w);
  }
}

extern "C" void kernel_launch(void* const* d_in, const int* in_sizes, int n_in,
                              void* d_out, int out_size, void* d_ws, size_t ws_size,
                              hipStream_t stream) {
  const float* x   = (const float*)d_in[0];
  const int*   ei  = (const int*)d_in[1];
  const float* W1  = (const float*)d_in[2];
  const float* a1s = (const float*)d_in[3];
  const float* a1d = (const float*)d_in[4];
  const float* b1  = (const float*)d_in[5];
  const float* W2  = (const float*)d_in[6];
  const float* a2s = (const float*)d_in[7];
  const float* a2d = (const float*)d_in[8];
  const float* b2  = (const float*)d_in[9];

  const int N = in_sizes[0] / 128;  // 100000
  const int E = in_sizes[1] / 2;    // 1600000
  const int* esrc = ei;
  const int* edst = ei + E;

  float* ws   = (float*)d_ws;
  __hip_bfloat16* h = (__hip_bfloat16*)ws;   // N*128 bf16 (slot sized N*128 f32)
  float* out1 = ws   + (size_t)N * 128;      // N*128 f32
  float* als  = out1 + (size_t)N * 128;      // N*4
  float* ald  = als  + (size_t)N * 4;        // N*4
  int* cnt    = (int*)(ald + (size_t)N * 4); // N
  int* rowptr = cnt + N;                     // N+1
  int* cursor = rowptr + N + 1;              // N
  int* bsum   = cursor + N;                  // 1024
  int* nbr    = bsum + 1024;                 // E+N
  size_t off = ((size_t)((nbr + E + N) - (int*)ws) + 3) & ~(size_t)3;
  uint4* wsw1 = (uint4*)((int*)ws + off);    // 144*16 uint4
  uint4* wsw2 = wsw1 + 144 * 16;             // 80*16 uint4

  float* outF = (float*)d_out;               // N*64

  const int total = E + N;
  const int nb = (N + 1023) / 1024;
  const int nbuild = 1280;
  const int ngemm1 = (N + 127) / 128;

  // ---- setup (W preps + cnt zero) + CSR count/scan ----
  const int zb = ((N >> 2) + 255) / 256;
  k_setup<<<14 + zb, 256, 0, stream>>>(W1, a1s, a1d, wsw1, W2, a2s, a2d, wsw2, cnt, N);
  k_count<<<((E >> 2) + (E & 3) + 255) / 256, 256, 0, stream>>>(edst, cnt, E);
  k_scan_local<<<nb, 256, 0, stream>>>(cnt, rowptr, bsum, N);
  k_scan_add2<<<(N + 256) / 256, 256, 0, stream>>>(bsum, nb, rowptr, cursor, N, total);

  // ---- Fused: CSR fill (blocks 0..nbuild) + layer-1 GEMM (rest) ----
  k_build_gemm1<<<nbuild + ngemm1, 256, 0, stream>>>(
      esrc, edst, cursor, nbr, E, nbuild, x, wsw1, h, als, ald, N);

  // ---- Layer 1 gather: H=4, C=32, concat -> [N,128], +b1, ELU ----
  k_gather_l1<<<(N + 7) / 8, 256, 0, stream>>>(rowptr, nbr, als, ald, h, b1, out1, N);

  // ---- Layer 2: H=1, C=64, mean(H=1) -> [N,64], +b2 ----
  k_mfma_gemm<64, 1><<<(N + 127) / 128, 256, 0, stream>>>(out1, wsw2, h, als, ald, N);
  k_gather_l2<<<(N + 7) / 8, 256, 0, stream>>>(rowptr, nbr, als, ald, h, b2, outF, N);
}

// Round 15
// 297.930 us; speedup vs baseline: 1.1683x; 1.0081x over previous
//
#include <hip/hip_runtime.h>
#include <hip/hip_bf16.h>
#include <math.h>

static constexpr float NEG_SLOPE = 0.2f;
static constexpr float NEG_BIG = -3.0e38f;  // finite sentinel: avoids (-inf)-(-inf)=NaN

typedef __attribute__((ext_vector_type(8))) short short8;  // 8 bf16 (4 VGPRs)
typedef __attribute__((ext_vector_type(4))) float f32x4;

__device__ __forceinline__ float blo(unsigned u) { return __uint_as_float(u << 16); }
__device__ __forceinline__ float bhi(unsigned u) { return __uint_as_float(u & 0xffff0000u); }
// hi bf16 read WITHOUT masking: low 16 bits are <=2^-8 relative mantissa noise.
__device__ __forceinline__ float bhiraw(unsigned u) { return __uint_as_float(u); }
__device__ __forceinline__ unsigned pack2(float a, float b) {
  __hip_bfloat162 t = __float22bfloat162_rn(make_float2(a, b));
  union { __hip_bfloat162 b; unsigned u; } v;
  v.b = t;
  return v.u;
}

#define FMA8(V, A)                         \
  acc[0] = fmaf(blo((V).x), (A), acc[0]);  \
  acc[1] = fmaf(bhi((V).x), (A), acc[1]);  \
  acc[2] = fmaf(blo((V).y), (A), acc[2]);  \
  acc[3] = fmaf(bhi((V).y), (A), acc[3]);  \
  acc[4] = fmaf(blo((V).z), (A), acc[4]);  \
  acc[5] = fmaf(bhi((V).z), (A), acc[5]);  \
  acc[6] = fmaf(blo((V).w), (A), acc[6]);  \
  acc[7] = fmaf(bhi((V).w), (A), acc[7])

#define FMA8R(V, A)                           \
  acc[0] = fmaf(blo((V).x), (A), acc[0]);     \
  acc[1] = fmaf(bhiraw((V).x), (A), acc[1]);  \
  acc[2] = fmaf(blo((V).y), (A), acc[2]);     \
  acc[3] = fmaf(bhiraw((V).y), (A), acc[3]);  \
  acc[4] = fmaf(blo((V).z), (A), acc[4]);     \
  acc[5] = fmaf(bhiraw((V).z), (A), acc[5]);  \
  acc[6] = fmaf(blo((V).w), (A), acc[6]);     \
  acc[7] = fmaf(bhiraw((V).w), (A), acc[7])

// ---- W prep (device fn): fp32 [k][col] -> bf16 swizzled [col][k] image + 16
// extra cols of WA = W@A so the GEMM emits logits as a free tile.
template <int BN, int HEADS>
__device__ void prep_w(const float* __restrict__ W, const float* __restrict__ as_,
                       const float* __restrict__ ad_, uint4* __restrict__ out, int i) {
  constexpr int XC = BN + 16;
  constexpr int C = BN / HEADS;
  if (i >= XC * 16) return;
  const int col = i >> 4;
  const int chunk = (i & 15) ^ (col & 7);
  float v[8];
  if (col < BN) {
#pragma unroll
    for (int t = 0; t < 8; ++t) v[t] = W[(size_t)(chunk * 8 + t) * BN + col];
  } else {
    const int j = col - BN;
#pragma unroll
    for (int t = 0; t < 8; ++t) v[t] = 0.f;
    if (j < 2 * HEADS) {
      const int hh = (HEADS == 4) ? (j & 3) : 0;
      const bool is_src = (HEADS == 4) ? (j < 4) : (j == 0);
      const float* av = (is_src ? as_ : ad_) + hh * C;
      const float* wb = W + hh * C;
#pragma unroll
      for (int t = 0; t < 8; ++t) {
        float s = 0.f;
        for (int c = 0; c < C; ++c) s = fmaf(wb[(size_t)(chunk * 8 + t) * BN + c], av[c], s);
        v[t] = s;
      }
    }
  }
  uint4 u;
  u.x = pack2(v[0], v[1]);
  u.y = pack2(v[2], v[3]);
  u.z = pack2(v[4], v[5]);
  u.w = pack2(v[6], v[7]);
  out[i] = u;
}

// Fused setup: blocks [0,9) prep W1; [9,14) prep W2; rest zero cnt.
__global__ void k_setup(const float* __restrict__ W1, const float* __restrict__ a1s,
                        const float* __restrict__ a1d, uint4* __restrict__ wsw1,
                        const float* __restrict__ W2, const float* __restrict__ a2s,
                        const float* __restrict__ a2d, uint4* __restrict__ wsw2,
                        int* __restrict__ cnt, int N) {
  const int b = blockIdx.x;
  const int tid = threadIdx.x;
  if (b < 9) {
    prep_w<128, 4>(W1, a1s, a1d, wsw1, b * 256 + tid);
  } else if (b < 14) {
    prep_w<64, 1>(W2, a2s, a2d, wsw2, (b - 9) * 256 + tid);
  } else {
    const int i = (b - 14) * 256 + tid;
    if (i < (N >> 2)) ((int4*)cnt)[i] = make_int4(0, 0, 0, 0);
    const int r = (N & ~3) + i;  // tail (N%4 elems)
    if (i < 4 && r < N) cnt[r] = 0;
  }
}

// ---- MFMA GEMM body: h = x@W (bf16), logits from extra tile. Reused LDS buf.
template <int BN, int HEADS>
__device__ void gemm_body(const float* __restrict__ x, const uint4* __restrict__ wsw,
                          __hip_bfloat16* __restrict__ h_out, float* __restrict__ als,
                          float* __restrict__ ald, int N, int bid) {
  constexpr int XC = BN + 16;
  constexpr int NTILES = BN / 16;
  constexpr int BUFSZ = (XC * 256 > 128 * 256) ? XC * 256 : 128 * 256;
  __shared__ unsigned char buf[BUFSZ];
  const int tid = threadIdx.x;
  const int lane = tid & 63;
  const int wid = tid >> 6;
  const int base = bid * 128;

  for (int it = 0; it < 8; ++it) {
    const int i = it * 256 + tid;
    const int r = i >> 4, c = i & 15;
    const int g = base + r;
    float4 f0 = make_float4(0.f, 0.f, 0.f, 0.f), f1 = f0;
    if (g < N) {
      const float* xp = x + (size_t)g * 128 + c * 8;
      f0 = *(const float4*)xp;
      f1 = *(const float4*)(xp + 4);
    }
    uint4 u;
    u.x = pack2(f0.x, f0.y);
    u.y = pack2(f0.z, f0.w);
    u.z = pack2(f1.x, f1.y);
    u.w = pack2(f1.z, f1.w);
    *(uint4*)(buf + r * 256 + ((c * 16) ^ ((r & 7) << 4))) = u;
  }
  __syncthreads();

  const int lg = lane >> 4;
  const int ll = lane & 15;
  union U { uint4 u; short8 s; };
  short8 afr[2][4];
#pragma unroll
  for (int rt = 0; rt < 2; ++rt) {
    const int row = wid * 32 + rt * 16 + ll;
    const unsigned char* rp = buf + row * 256;
    const int swz = (row & 7) << 4;
#pragma unroll
    for (int ks = 0; ks < 4; ++ks) {
      U t;
      t.u = *(const uint4*)(rp + ((ks * 64 + lg * 16) ^ swz));
      afr[rt][ks] = t.s;
    }
  }
  __syncthreads();  // done with X region; reuse buf for W

  {
    uint4* dst = (uint4*)buf;
    for (int i = tid; i < XC * 16; i += 256) dst[i] = wsw[i];
  }
  __syncthreads();

  f32x4 acc[2][NTILES + 1];
#pragma unroll
  for (int rt = 0; rt < 2; ++rt)
#pragma unroll
    for (int t = 0; t <= NTILES; ++t) acc[rt][t] = (f32x4){0.f, 0.f, 0.f, 0.f};

#pragma unroll
  for (int t = 0; t <= NTILES; ++t) {
    const int col = t * 16 + ll;
    const unsigned char* cp = buf + col * 256;
    const int swz = (col & 7) << 4;
#pragma unroll
    for (int ks = 0; ks < 4; ++ks) {
      U b;
      b.u = *(const uint4*)(cp + ((ks * 64 + lg * 16) ^ swz));
      acc[0][t] = __builtin_amdgcn_mfma_f32_16x16x32_bf16(afr[0][ks], b.s, acc[0][t], 0, 0, 0);
      acc[1][t] = __builtin_amdgcn_mfma_f32_16x16x32_bf16(afr[1][ks], b.s, acc[1][t], 0, 0, 0);
    }
  }

#pragma unroll
  for (int rt = 0; rt < 2; ++rt) {
#pragma unroll
    for (int r = 0; r < 4; ++r) {
      const int row = base + wid * 32 + rt * 16 + lg * 4 + r;
      if (row < N) {
        const float v = acc[rt][NTILES][r];
        if (HEADS == 4) {
          if (ll < 4) als[(size_t)row * 4 + ll] = v;
          else if (ll < 8) ald[(size_t)row * 4 + (ll - 4)] = v;
        } else {
          if (ll == 0) als[row] = v;
          else if (ll == 1) ald[row] = v;
        }
      }
    }
  }

  __syncthreads();
#pragma unroll
  for (int rt = 0; rt < 2; ++rt) {
#pragma unroll
    for (int t = 0; t < NTILES; ++t) {
#pragma unroll
      for (int r = 0; r < 4; ++r) {
        const float v = acc[rt][t][r];
        const float vn = __shfl_xor(v, 1, 64);
        if (!(lane & 1)) {
          const int row = wid * 32 + rt * 16 + lg * 4 + r;
          *(unsigned*)(buf + row * (BN * 2) + (t * 16 + ll) * 2) = pack2(v, vn);
        }
      }
    }
  }
  __syncthreads();
  {
    constexpr int U4 = 128 * BN / 8;
    constexpr int U4R = BN / 8;
    for (int i = tid; i < U4; i += 256) {
      const int row = i / U4R;
      const int g = base + row;
      if (g < N)
        *(uint4*)((unsigned short*)h_out + (size_t)g * BN + (i % U4R) * 8) = ((uint4*)buf)[i];
    }
  }
}

template <int BN, int HEADS>
__global__ __launch_bounds__(256) void k_mfma_gemm(
    const float* __restrict__ x, const uint4* __restrict__ wsw,
    __hip_bfloat16* __restrict__ h_out, float* __restrict__ als,
    float* __restrict__ ald, int N) {
  gemm_body<BN, HEADS>(x, wsw, h_out, als, ald, N, blockIdx.x);
}

// ---- CSR build body: 8 parts, p = bid&7 -> each part's nbr region is written
// by blocks on exactly ONE XCD (round-robin bid->XCD), so dirty lines stay in
// that XCD's L2 and coalesce ~16 writes before writeback.
__device__ void build_body(const int* __restrict__ esrc, const int* __restrict__ edst,
                           int* __restrict__ cursor, int* __restrict__ nbr, int E, int N,
                           int bid, int nbuild) {
  constexpr int NPARTS = 8;
  const int p = bid & 7;
  const int span = (N + NPARTS - 1) / NPARTS;
  const int lo = p * span;
  const int hi = min(N, lo + span);
  const int gid = (bid >> 3) * 256 + (int)threadIdx.x;
  const int stride = (nbuild >> 3) * 256;
  const int E4 = E >> 2;
  for (int i = gid; i < E4; i += stride) {
    const int4 d4 = ((const int4*)edst)[i];
    const int4 s4 = ((const int4*)esrc)[i];
    if (d4.x >= lo && d4.x < hi) nbr[atomicAdd(cursor + d4.x, 1)] = s4.x;
    if (d4.y >= lo && d4.y < hi) nbr[atomicAdd(cursor + d4.y, 1)] = s4.y;
    if (d4.z >= lo && d4.z < hi) nbr[atomicAdd(cursor + d4.z, 1)] = s4.z;
    if (d4.w >= lo && d4.w < hi) nbr[atomicAdd(cursor + d4.w, 1)] = s4.w;
  }
  for (int i = E4 * 4 + gid; i < E + N; i += stride) {
    const int d = i < E ? edst[i] : i - E;
    if (d >= lo && d < hi) {
      const int sn = i < E ? esrc[i] : i - E;
      nbr[atomicAdd(cursor + d, 1)] = sn;
    }
  }
}

// Fused: blocks [0,nbuild) build the CSR; blocks [nbuild,..) run layer-1 GEMM.
// Independent work -> memory-bound build overlaps compute-bound MFMA GEMM.
__global__ __launch_bounds__(256) void k_build_gemm1(
    const int* __restrict__ esrc, const int* __restrict__ edst,
    int* __restrict__ cursor, int* __restrict__ nbr, int E, int nbuild,
    const float* __restrict__ x, const uint4* __restrict__ wsw,
    __hip_bfloat16* __restrict__ h_out, float* __restrict__ als,
    float* __restrict__ ald, int N) {
  const int b = (int)blockIdx.x;
  if (b < nbuild) {
    build_body(esrc, edst, cursor, nbr, E, N, b, nbuild);
    return;
  }
  gemm_body<128, 4>(x, wsw, h_out, als, ald, N, b - nbuild);
}

// ---------------- CSR count / scan ----------------
__global__ void k_count(const int* __restrict__ edst, int* __restrict__ cnt, int E) {
  int i = blockIdx.x * blockDim.x + threadIdx.x;
  const int E4 = E >> 2;
  if (i < E4) {
    const int4 d4 = ((const int4*)edst)[i];
    atomicAdd(cnt + d4.x, 1);
    atomicAdd(cnt + d4.y, 1);
    atomicAdd(cnt + d4.z, 1);
    atomicAdd(cnt + d4.w, 1);
  } else {
    const int r = E4 * 4 + (i - E4);
    if (r < E) atomicAdd(cnt + edst[r], 1);
  }
}

// +1 folded in (self-loop); cnt zeroed in k_setup.
__global__ void k_scan_local(const int* __restrict__ cnt, int* __restrict__ rowptr,
                             int* __restrict__ bsum, int N) {
  __shared__ int lds[256];
  const int tid = threadIdx.x;
  const int base = blockIdx.x * 1024;
  int vals[4], tsum = 0;
#pragma unroll
  for (int q = 0; q < 4; ++q) {
    int i = base + tid * 4 + q;
    vals[q] = (i < N) ? cnt[i] + 1 : 0;
    tsum += vals[q];
  }
  lds[tid] = tsum;
  __syncthreads();
  for (int off = 1; off < 256; off <<= 1) {
    int t = (tid >= off) ? lds[tid - off] : 0;
    __syncthreads();
    lds[tid] += t;
    __syncthreads();
  }
  int run = lds[tid] - tsum;
  if (tid == 255) bsum[blockIdx.x] = lds[255];
#pragma unroll
  for (int q = 0; q < 4; ++q) {
    int i = base + tid * 4 + q;
    if (i < N) rowptr[i] = run;
    run += vals[q];
  }
}

// Fused bsum-scan + add: every block redundantly scans bsum (<=128 entries).
__global__ void k_scan_add2(const int* __restrict__ bsum, int nb,
                            int* __restrict__ rowptr, int* __restrict__ cursor,
                            int N, int total) {
  __shared__ int pref[128];
  const int tid = threadIdx.x;
  int own = 0;
  if (tid < 128) {
    own = (tid < nb) ? bsum[tid] : 0;
    pref[tid] = own;
  }
  __syncthreads();
  for (int off = 1; off < 128; off <<= 1) {
    int t = (tid >= off && tid < 128) ? pref[tid - off] : 0;
    __syncthreads();
    if (tid < 128) pref[tid] += t;
    __syncthreads();
  }
  if (tid < 128) pref[tid] -= own;  // exclusive
  __syncthreads();
  const int i = blockIdx.x * blockDim.x + tid;
  if (i < N) {
    int r = rowptr[i] + pref[i >> 10];
    rowptr[i] = r;
    cursor[i] = r;
  } else if (i == N) {
    rowptr[N] = total;
  }
}

// ---------------- Gather layer 1: H=4, C=32; two nodes/wave; 8-edge batches ----
__global__ void k_gather_l1(const int* __restrict__ rowptr, const int* __restrict__ nbr,
                            const float* __restrict__ als, const float* __restrict__ ald,
                            const __hip_bfloat16* __restrict__ hfeat,
                            const float* __restrict__ bias,
                            float* __restrict__ out, int N) {
  __shared__ float atab[4][2][4][40];    // [wave][half][head][edge]
  __shared__ unsigned otab[4][2][32];    // [wave][half][edge] byte offsets
  const int lane = threadIdx.x & 63;
  const int wid = threadIdx.x >> 6;
  const int half = lane >> 5;
  const int l32 = lane & 31;
  const int node = (int)((blockIdx.x * blockDim.x + threadIdx.x) >> 6) * 2 + half;
  const bool valid = node < N;
  int start = 0, end = 0;
  if (valid) {
    start = rowptr[node];
    end = rowptr[node + 1];
  }
  const int deg = end - start;
  const float4 aldd = valid ? ((const float4*)ald)[node] : make_float4(0.f, 0.f, 0.f, 0.f);

  float t[4];
  int myn = 0;
  {
    const int j = start + l32;
    if (j < end) {
      myn = nbr[j];
      const float4 av = ((const float4*)als)[myn];
      const float tr[4] = {av.x + aldd.x, av.y + aldd.y, av.z + aldd.z, av.w + aldd.w};
#pragma unroll
      for (int h = 0; h < 4; ++h) t[h] = tr[h] >= 0.f ? tr[h] : NEG_SLOPE * tr[h];
    } else {
#pragma unroll
      for (int h = 0; h < 4; ++h) t[h] = NEG_BIG;
    }
  }
  otab[wid][half][l32] = (unsigned)myn << 8;  // 256B rows

  float Mh[4], rden[4], myex[4];
  if (deg <= 32) {
#pragma unroll
    for (int h = 0; h < 4; ++h) {
      float M = t[h];
#pragma unroll
      for (int off = 1; off < 32; off <<= 1) M = fmaxf(M, __shfl_xor(M, off, 64));
      const float e = __expf(t[h] - M);
      float sum = e;
#pragma unroll
      for (int off = 1; off < 32; off <<= 1) sum += __shfl_xor(sum, off, 64);
      Mh[h] = M;
      rden[h] = 1.f / sum;
      myex[h] = e * rden[h];
    }
  } else {
    float m[4], s[4];
#pragma unroll
    for (int h = 0; h < 4; ++h) {
      m[h] = t[h];
      s[h] = (t[h] > NEG_BIG) ? 1.f : 0.f;
    }
    for (int b = start + 32; b < end; b += 32) {
      const int j = b + l32;
      if (j < end) {
        const int sn = nbr[j];
        const float4 av = ((const float4*)als)[sn];
        const float tr[4] = {av.x + aldd.x, av.y + aldd.y, av.z + aldd.z, av.w + aldd.w};
#pragma unroll
        for (int h = 0; h < 4; ++h) {
          const float tv = tr[h] >= 0.f ? tr[h] : NEG_SLOPE * tr[h];
          const float M = fmaxf(m[h], tv);
          s[h] = s[h] * __expf(m[h] - M) + __expf(tv - M);
          m[h] = M;
        }
      }
    }
#pragma unroll
    for (int h = 0; h < 4; ++h) {
      float M = m[h];
#pragma unroll
      for (int off = 1; off < 32; off <<= 1) M = fmaxf(M, __shfl_xor(M, off, 64));
      float e = s[h] * __expf(m[h] - M);
#pragma unroll
      for (int off = 1; off < 32; off <<= 1) e += __shfl_xor(e, off, 64);
      Mh[h] = M;
      rden[h] = 1.f / e;
      myex[h] = __expf(t[h] - M) * rden[h];
    }
  }
#pragma unroll
  for (int h = 0; h < 4; ++h) atab[wid][half][h][l32] = myex[h];

  // pass C: 8 edges per iteration (2 slots x 4 batched loads in flight)
  const int sub = l32 >> 4;
  const int q = l32 & 15;
  const int head = q >> 2;
  const char* hq = (const char*)hfeat + q * 16;
  float acc[8];
#pragma unroll
  for (int k = 0; k < 8; ++k) acc[k] = 0.f;

  const int nq = deg < 32 ? deg : 32;
  const float* ap = &atab[wid][half][head][0];
  const unsigned* op = &otab[wid][half][0];
  for (int j0 = 0; j0 < nq; j0 += 8) {
    const float a0 = ap[j0 + sub];
    const float a1 = ap[j0 + 2 + sub];
    const float a2 = ap[j0 + 4 + sub];
    const float a3 = ap[j0 + 6 + sub];
    const uint4 v0 = *(const uint4*)(hq + op[j0 + sub]);
    const uint4 v1 = *(const uint4*)(hq + op[j0 + 2 + sub]);
    const uint4 v2 = *(const uint4*)(hq + op[j0 + 4 + sub]);
    const uint4 v3 = *(const uint4*)(hq + op[j0 + 6 + sub]);
    FMA8R(v0, a0);
    FMA8R(v1, a1);
    FMA8R(v2, a2);
    FMA8R(v3, a3);
  }
  if (deg > 32) {
    const float Mm = head == 0 ? Mh[0] : head == 1 ? Mh[1] : head == 2 ? Mh[2] : Mh[3];
    const float rd = head == 0 ? rden[0] : head == 1 ? rden[1] : head == 2 ? rden[2] : rden[3];
    const float ad_ = head == 0 ? aldd.x : head == 1 ? aldd.y : head == 2 ? aldd.z : aldd.w;
    for (int j0 = 32; j0 < deg; j0 += 2) {
      const int j = j0 + sub;
      float a = 0.f;
      int sn = 0;
      if (j < deg) {
        sn = nbr[start + j];
        const float4 av = ((const float4*)als)[sn];
        const float as_ = head == 0 ? av.x : head == 1 ? av.y : head == 2 ? av.z : av.w;
        float tv = as_ + ad_;
        tv = tv >= 0.f ? tv : NEG_SLOPE * tv;
        a = __expf(tv - Mm) * rd;
      }
      const uint4 v = *(const uint4*)(hq + (size_t)sn * 256);
      FMA8R(v, a);
    }
  }

#pragma unroll
  for (int k = 0; k < 8; ++k) acc[k] += __shfl_xor(acc[k], 16, 64);
  if (valid && sub == 0) {
    const float4 b0 = ((const float4*)bias)[q * 2];
    const float4 b1 = ((const float4*)bias)[q * 2 + 1];
    float r[8] = {acc[0] + b0.x, acc[1] + b0.y, acc[2] + b0.z, acc[3] + b0.w,
                  acc[4] + b1.x, acc[5] + b1.y, acc[6] + b1.z, acc[7] + b1.w};
#pragma unroll
    for (int k = 0; k < 8; ++k) r[k] = r[k] > 0.f ? r[k] : __expf(r[k]) - 1.f;
    float4* opo = (float4*)(out + (size_t)node * 128 + q * 8);
    opo[0] = make_float4(r[0], r[1], r[2], r[3]);
    opo[1] = make_float4(r[4], r[5], r[6], r[7]);
  }
}

// ---------------- Gather layer 2: H=1, C=64; two nodes/wave; 16-edge batches ----
__global__ void k_gather_l2(const int* __restrict__ rowptr, const int* __restrict__ nbr,
                            const float* __restrict__ als, const float* __restrict__ ald,
                            const __hip_bfloat16* __restrict__ hfeat,
                            const float* __restrict__ bias,
                            float* __restrict__ out, int N) {
  __shared__ float2 atab[4][2][36];  // {alpha, off}
  const int lane = threadIdx.x & 63;
  const int wid = threadIdx.x >> 6;
  const int half = lane >> 5;
  const int l32 = lane & 31;
  const int node = (int)((blockIdx.x * blockDim.x + threadIdx.x) >> 6) * 2 + half;
  const bool valid = node < N;
  int start = 0, end = 0;
  if (valid) {
    start = rowptr[node];
    end = rowptr[node + 1];
  }
  const int deg = end - start;
  const float ald0 = valid ? ald[node] : 0.f;

  float t = NEG_BIG;
  int myn = 0;
  {
    const int j = start + l32;
    if (j < end) {
      myn = nbr[j];
      float tv = als[myn] + ald0;
      t = tv >= 0.f ? tv : NEG_SLOPE * tv;
    }
  }

  float M, rden, myal;
  if (deg <= 32) {
    M = t;
#pragma unroll
    for (int off = 1; off < 32; off <<= 1) M = fmaxf(M, __shfl_xor(M, off, 64));
    const float e = __expf(t - M);
    float sum = e;
#pragma unroll
    for (int off = 1; off < 32; off <<= 1) sum += __shfl_xor(sum, off, 64);
    rden = 1.f / sum;
    myal = e * rden;
  } else {
    float m = t, s = (t > NEG_BIG) ? 1.f : 0.f;
    for (int b = start + 32; b < end; b += 32) {
      const int j = b + l32;
      if (j < end) {
        float tv = als[nbr[j]] + ald0;
        tv = tv >= 0.f ? tv : NEG_SLOPE * tv;
        const float Mn = fmaxf(m, tv);
        s = s * __expf(m - Mn) + __expf(tv - Mn);
        m = Mn;
      }
    }
    M = m;
#pragma unroll
    for (int off = 1; off < 32; off <<= 1) M = fmaxf(M, __shfl_xor(M, off, 64));
    float e = s * __expf(m - M);
#pragma unroll
    for (int off = 1; off < 32; off <<= 1) e += __shfl_xor(e, off, 64);
    rden = 1.f / e;
    myal = __expf(t - M) * rden;
  }
  atab[wid][half][l32] = make_float2(myal, __int_as_float(myn << 7));  // 128B rows

  const int sub = l32 >> 3;  // 4 edge slots
  const int q = l32 & 7;
  const char* hq = (const char*)hfeat + q * 16;
  float acc[8];
#pragma unroll
  for (int k = 0; k < 8; ++k) acc[k] = 0.f;

  const int nq = deg < 32 ? deg : 32;
  const float2* ap = &atab[wid][half][0];
  for (int j0 = 0; j0 < nq; j0 += 16) {
    const float2 o0 = ap[j0 + sub];
    const float2 o1 = ap[j0 + 4 + sub];
    const float2 o2 = ap[j0 + 8 + sub];
    const float2 o3 = ap[j0 + 12 + sub];
    const uint4 v0 = *(const uint4*)(hq + (unsigned)__float_as_int(o0.y));
    const uint4 v1 = *(const uint4*)(hq + (unsigned)__float_as_int(o1.y));
    const uint4 v2 = *(const uint4*)(hq + (unsigned)__float_as_int(o2.y));
    const uint4 v3 = *(const uint4*)(hq + (unsigned)__float_as_int(o3.y));
    FMA8(v0, o0.x);
    FMA8(v1, o1.x);
    FMA8(v2, o2.x);
    FMA8(v3, o3.x);
  }
  if (deg > 32) {
    for (int j0 = 32; j0 < deg; j0 += 4) {
      const int j = j0 + sub;
      float a = 0.f;
      int sn = 0;
      if (j < deg) {
        sn = nbr[start + j];
        float tv = als[sn] + ald0;
        tv = tv >= 0.f ? tv : NEG_SLOPE * tv;
        a = __expf(tv - M) * rden;
      }
      const uint4 v = *(const uint4*)(hq + (size_t)sn * 128);
      FMA8(v, a);
    }
  }

#pragma unroll
  for (int k = 0; k < 8; ++k) {
    acc[k] += __shfl_xor(acc[k], 8, 64);
    acc[k] += __shfl_xor(acc[k], 16, 64);
  }
  if (valid && sub == 0) {
    const float4 b0 = ((const float4*)bias)[q * 2];
    const float4 b1 = ((const float4*)bias)[q * 2 + 1];
    float4* opo = (float4*)(out + (size_t)node * 64 + q * 8);
    opo[0] = make_float4(acc[0] + b0.x, acc[1] + b0.y, acc[2] + b0.z, acc[3] + b0.w);
    opo[1] = make_float4(acc[4] + b1.x, acc[5] + b1.y, acc[6] + b1.z, acc[7] + b1.w);
  }
}

extern "C" void kernel_launch(void* const* d_in, const int* in_sizes, int n_in,
                              void* d_out, int out_size, void* d_ws, size_t ws_size,
                              hipStream_t stream) {
  const float* x   = (const float*)d_in[0];
  const int*   ei  = (const int*)d_in[1];
  const float* W1  = (const float*)d_in[2];
  const float* a1s = (const float*)d_in[3];
  const float* a1d = (const float*)d_in[4];
  const float* b1  = (const float*)d_in[5];
  const float* W2  = (const float*)d_in[6];
  const float* a2s = (const float*)d_in[7];
  const float* a2d = (const float*)d_in[8];
  const float* b2  = (const float*)d_in[9];

  const int N = in_sizes[0] / 128;  // 100000
  const int E = in_sizes[1] / 2;    // 1600000
  const int* esrc = ei;
  const int* edst = ei + E;

  float* ws   = (float*)d_ws;
  __hip_bfloat16* h = (__hip_bfloat16*)ws;   // N*128 bf16 (slot sized N*128 f32)
  float* out1 = ws   + (size_t)N * 128;      // N*128 f32
  float* als  = out1 + (size_t)N * 128;      // N*4
  float* ald  = als  + (size_t)N * 4;        // N*4
  int* cnt    = (int*)(ald + (size_t)N * 4); // N
  int* rowptr = cnt + N;                     // N+1
  int* cursor = rowptr + N + 1;              // N
  int* bsum   = cursor + N;                  // 1024
  int* nbr    = bsum + 1024;                 // E+N
  size_t off = ((size_t)((nbr + E + N) - (int*)ws) + 3) & ~(size_t)3;
  uint4* wsw1 = (uint4*)((int*)ws + off);    // 144*16 uint4
  uint4* wsw2 = wsw1 + 144 * 16;             // 80*16 uint4

  float* outF = (float*)d_out;               // N*64

  const int total = E + N;
  const int nb = (N + 1023) / 1024;
  const int nbuild = 1280;
  const int ngemm1 = (N + 127) / 128;

  // ---- setup (W preps + cnt zero) + CSR count/scan ----
  const int zb = ((N >> 2) + 255) / 256;
  k_setup<<<14 + zb, 256, 0, stream>>>(W1, a1s, a1d, wsw1, W2, a2s, a2d, wsw2, cnt, N);
  k_count<<<((E >> 2) + (E & 3) + 255) / 256, 256, 0, stream>>>(edst, cnt, E);
  k_scan_local<<<nb, 256, 0, stream>>>(cnt, rowptr, bsum, N);
  k_scan_add2<<<(N + 256) / 256, 256, 0, stream>>>(bsum, nb, rowptr, cursor, N, total);

  // ---- Fused: CSR fill (blocks 0..nbuild) + layer-1 GEMM (rest) ----
  k_build_gemm1<<<nbuild + ngemm1, 256, 0, stream>>>(
      esrc, edst, cursor, nbr, E, nbuild, x, wsw1, h, als, ald, N);

  // ---- Layer 1 gather: H=4, C=32, concat -> [N,128], +b1, ELU ----
  k_gather_l1<<<(N + 7) / 8, 256, 0, stream>>>(rowptr, nbr, als, ald, h, b1, out1, N);

  // ---- Layer 2: H=1, C=64, mean(H=1) -> [N,64], +b2 ----
  k_mfma_gemm<64, 1><<<(N + 127) / 128, 256, 0, stream>>>(out1, wsw2, h, als, ald, N);
  k_gather_l2<<<(N + 7) / 8, 256, 0, stream>>>(rowptr, nbr, als, ald, h, b2, outF, N);
}